// Round 9
// baseline (758.606 us; speedup 1.0000x reference)
//
#include <hip/hip_runtime.h>
#include <math.h>
#include <stdint.h>

typedef _Float16 f16;
typedef f16   f16x8 __attribute__((ext_vector_type(8)));
typedef f16   f16x4 __attribute__((ext_vector_type(4)));
typedef float f32x4 __attribute__((ext_vector_type(4)));

constexpr int Bc = 2, Sc = 2048, Dc = 1024, Hc = 16, HDc = 64;
constexpr size_t PROJ = (size_t)Bc * Sc * Dc;     // 4,194,304
constexpr size_t WN   = (size_t)Dc * Dc;          // 1,048,576

// async 16B global->LDS (wave-uniform LDS base + lane*16 layout required)
__device__ __forceinline__ void gload_lds16(const void* g, void* l) {
    unsigned int off = (unsigned int)(uintptr_t)l;
    auto lp = (__attribute__((address_space(3))) unsigned int*)(uintptr_t)off;
    auto gp = (const __attribute__((address_space(1))) unsigned int*)(uintptr_t)g;
    __builtin_amdgcn_global_load_lds(gp, lp, 16, 0, 0);
}

// ---------------------------------------------------------------------------
// Band-complement zero fill: 32 rows/block; per row zero [0,a0) and [a1,2048)
// floats where a0/a1 are 32-float (128 B) aligned around the |i-j|<=64 band.
// ---------------------------------------------------------------------------
__device__ __forceinline__ void fill_rows32(float* __restrict__ attn, int grow0, int t) {
    const uint4 z = {0u, 0u, 0u, 0u};
    for (int rr = 0; rr < 32; ++rr) {
        const int gr = grow0 + rr;
        const int i = gr & (Sc - 1);
        const int lo = (i > 64) ? (i - 64) : 0;
        const int a0 = lo & ~31;
        const int hi = (i < Sc - 65) ? (i + 64) : (Sc - 1);
        int a1 = (hi + 32) & ~31; if (a1 > Sc) a1 = Sc;
        uint4* rowp = (uint4*)(attn + (size_t)gr * Sc);
        const int n4L = a0 >> 2;
        const int r0  = a1 >> 2;
        const int tot = n4L + (512 - r0);
        for (int idx = t; idx < tot; idx += 256) {
            const int p = (idx < n4L) ? idx : (r0 + idx - n4L);
            rowp[p] = z;
        }
    }
}

// ---------------------------------------------------------------------------
// fp32 -> fp16 pack: x (4096 blocks) + 4 weight tensors (4x1024 blocks)
// + 1 guard block zeroing the 512B margins around vT.
// ---------------------------------------------------------------------------
__global__ __launch_bounds__(256)
void pack_all(const float* __restrict__ x,
              const float* __restrict__ w0, const float* __restrict__ w1,
              const float* __restrict__ w2, const float* __restrict__ w3,
              f16* __restrict__ xd, f16* __restrict__ wd, f16* __restrict__ vT) {
    const int bid = blockIdx.x;
    if (bid == 8192) {
        const uint4 z = {0u, 0u, 0u, 0u};
        uint4* pre  = (uint4*)(vT - 256);                      // 512 B
        uint4* post = (uint4*)(vT + (size_t)4 * 1024 * 1024);  // 512 B
        const int t = threadIdx.x;
        if (t < 32) pre[t] = z;
        else if (t < 64) post[t - 32] = z;
        return;
    }
    const float* src;
    f16* dst;
    int off4;
    if (bid < 4096) {
        src = x; dst = xd; off4 = bid;
    } else {
        const int wi = (bid - 4096) >> 10;
        const int r  = (bid - 4096) & 1023;
        src = (wi == 0) ? w0 : (wi == 1) ? w1 : (wi == 2) ? w2 : w3;
        dst = wd + (size_t)wi * WN;
        off4 = r;
    }
    const int i = off4 * 256 + threadIdx.x;
    float4 f = ((const float4*)src)[i];
    f16x4 h = {(f16)f.x, (f16)f.y, (f16)f.z, (f16)f.w};
    ((f16x4*)dst)[i] = h;
}

// ---------------------------------------------------------------------------
// QKV GEMM (+ interleaved fill blocks, uniform 3:5 -> no all-fill tail).
// GEMM: C[M,N]=A@W^T+bias, BM=BN=128, BK=32, 256 thr, 4 waves.
// V (ten==2) stored TRANSPOSED: vT[(b*1024+col)][token&2047].
// ---------------------------------------------------------------------------
template <typename OutT, bool WITH_FILL>
__global__ __launch_bounds__(256, 3)
void gemm_mega(const f16* __restrict__ A, const f16* __restrict__ W,
               const float* __restrict__ b0, const float* __restrict__ b1,
               const float* __restrict__ b2,
               OutT* __restrict__ o0, OutT* __restrict__ o1, OutT* __restrict__ o2,
               float* __restrict__ fill, int n_ct) {
    constexpr int K = 1024, N = 1024;
    const int bid = blockIdx.x;
    const int t = threadIdx.x;

    int gid = bid;
    if (WITH_FILL) {
        const int g8 = bid >> 3, l8 = bid & 7;
        if (l8 < 3) {
            gid = g8 * 3 + l8;                    // [0,768)
        } else {
            fill_rows32(fill, (g8 * 5 + (l8 - 3)) * 32, t);   // fid [0,1280)
            return;
        }
    }

    __shared__ f16 sA[128 * 32];
    __shared__ f16 sB[128 * 32];

    const int w = t >> 6, l = t & 63, l15 = l & 15, quad = l >> 4;
    const int col_t = gid % n_ct, row_t = gid / n_ct;
    const int row0 = row_t * 128, col0 = col_t * 128;
    const int wr = w >> 1, wc = w & 1;

    f32x4 acc[4][4];
    #pragma unroll
    for (int i = 0; i < 4; ++i)
        #pragma unroll
        for (int j = 0; j < 4; ++j) acc[i][j] = (f32x4){0.f, 0.f, 0.f, 0.f};

    const int arow = t >> 2;          // 0..63
    const int koff = (t & 3) * 8;     // 8 f16 = 16B
    const f16* ga = A + (size_t)(row0 + arow) * K + koff;
    const f16* gb = W + (size_t)(col0 + arow) * K + koff;
    f16* lA1 = sA + w * 512;          // wave-uniform LDS bases
    f16* lA2 = sA + 2048 + w * 512;
    f16* lB1 = sB + w * 512;
    f16* lB2 = sB + 2048 + w * 512;

    for (int k0 = 0; k0 < K; k0 += 32) {
        gload_lds16(ga + k0, lA1);
        gload_lds16(ga + (size_t)64 * K + k0, lA2);
        gload_lds16(gb + k0, lB1);
        gload_lds16(gb + (size_t)64 * K + k0, lB2);
        __syncthreads();

        f16x8 af[4], bf[4];
        #pragma unroll
        for (int mi = 0; mi < 4; ++mi)
            af[mi] = *(const f16x8*)&sA[(wr * 64 + mi * 16 + l15) * 32 + quad * 8];
        #pragma unroll
        for (int ni = 0; ni < 4; ++ni)
            bf[ni] = *(const f16x8*)&sB[(wc * 64 + ni * 16 + l15) * 32 + quad * 8];
        #pragma unroll
        for (int mi = 0; mi < 4; ++mi)
            #pragma unroll
            for (int ni = 0; ni < 4; ++ni)
                acc[mi][ni] = __builtin_amdgcn_mfma_f32_16x16x32_f16(af[mi], bf[ni], acc[mi][ni], 0, 0, 0);
        __syncthreads();
    }

    const int ten = col0 >> 10;                 // tile never straddles tensors
    const float* bias = (ten == 0) ? b0 : (ten == 1) ? b1 : b2;
    OutT* out = (ten == 0) ? o0 : (ten == 1) ? o1 : o2;
    const int nc0 = col0 & (N - 1);

    if constexpr (WITH_FILL) {
        if (ten == 2) {
            // transposed V store: lane holds tokens tok..tok+3 for column colv
            f16* vout = reinterpret_cast<f16*>(o2);
            #pragma unroll
            for (int mi = 0; mi < 4; ++mi)
                #pragma unroll
                for (int ni = 0; ni < 4; ++ni) {
                    const int tok  = row0 + wr * 64 + mi * 16 + quad * 4;
                    const int colv = nc0 + wc * 64 + ni * 16 + l15;
                    const float bvv = bias[colv];
                    f16x4 h4 = {(f16)(acc[mi][ni][0] + bvv), (f16)(acc[mi][ni][1] + bvv),
                                (f16)(acc[mi][ni][2] + bvv), (f16)(acc[mi][ni][3] + bvv)};
                    const int bb = tok >> 11;
                    *(f16x4*)&vout[((size_t)(bb * 1024 + colv)) * 2048 + (tok & 2047)] = h4;
                }
            return;
        }
    }

    #pragma unroll
    for (int mi = 0; mi < 4; ++mi)
        #pragma unroll
        for (int ni = 0; ni < 4; ++ni) {
            const int rbase = row0 + wr * 64 + mi * 16 + quad * 4;
            const int col = nc0 + wc * 64 + ni * 16 + l15;
            const float bv = bias[col];
            #pragma unroll
            for (int r = 0; r < 4; ++r)
                out[(size_t)(rbase + r) * N + col] = (OutT)(acc[mi][ni][r] + bv);
        }
}

// ---------------------------------------------------------------------------
// O-projection GEMM, BM=64 x BN=128.
// ---------------------------------------------------------------------------
__global__ __launch_bounds__(256, 3)
void gemm_o64(const f16* __restrict__ A, const f16* __restrict__ W,
              const float* __restrict__ bias, float* __restrict__ out) {
    constexpr int K = 1024, N = 1024;
    const int t = threadIdx.x;
    const int gid = blockIdx.x;

    __shared__ f16 sA[64 * 32];
    __shared__ f16 sB[128 * 32];

    const int w = t >> 6, l = t & 63, l15 = l & 15, quad = l >> 4;
    const int col_t = gid & 7, row_t = gid >> 3;
    const int row0 = row_t * 64, col0 = col_t * 128;

    f32x4 acc[4][2];
    #pragma unroll
    for (int i = 0; i < 4; ++i)
        #pragma unroll
        for (int j = 0; j < 2; ++j) acc[i][j] = (f32x4){0.f, 0.f, 0.f, 0.f};

    const int arow = t >> 2;          // 0..63
    const int koff = (t & 3) * 8;
    const f16* ga = A + (size_t)(row0 + arow) * K + koff;
    const f16* gb = W + (size_t)(col0 + arow) * K + koff;
    f16* lA1 = sA + w * 512;
    f16* lB1 = sB + w * 512;
    f16* lB2 = sB + 2048 + w * 512;

    for (int k0 = 0; k0 < K; k0 += 32) {
        gload_lds16(ga + k0, lA1);
        gload_lds16(gb + k0, lB1);
        gload_lds16(gb + (size_t)64 * K + k0, lB2);
        __syncthreads();

        f16x8 af[4], bf[2];
        #pragma unroll
        for (int mi = 0; mi < 4; ++mi)
            af[mi] = *(const f16x8*)&sA[(mi * 16 + l15) * 32 + quad * 8];
        #pragma unroll
        for (int ni = 0; ni < 2; ++ni)
            bf[ni] = *(const f16x8*)&sB[(w * 32 + ni * 16 + l15) * 32 + quad * 8];
        #pragma unroll
        for (int mi = 0; mi < 4; ++mi)
            #pragma unroll
            for (int ni = 0; ni < 2; ++ni)
                acc[mi][ni] = __builtin_amdgcn_mfma_f32_16x16x32_f16(af[mi], bf[ni], acc[mi][ni], 0, 0, 0);
        __syncthreads();
    }

    #pragma unroll
    for (int mi = 0; mi < 4; ++mi)
        #pragma unroll
        for (int ni = 0; ni < 2; ++ni) {
            const int rbase = row0 + mi * 16 + quad * 4;
            const int col = col0 + w * 32 + ni * 16 + l15;
            const float bv = bias[col];
            #pragma unroll
            for (int r = 0; r < 4; ++r)
                out[(size_t)(rbase + r) * N + col] = acc[mi][ni][r] + bv;
        }
}

// ---------------------------------------------------------------------------
// Fused band attention (+ interleaved fill blocks, uniform 4:3 in groups of 7).
// Q in registers; K/vT staged in LDS (52 KB -> 3 blocks/CU).
// ---------------------------------------------------------------------------
__global__ __launch_bounds__(256, 3)
void attn_fused(const f16* __restrict__ qb, const f16* __restrict__ kb,
                const f16* __restrict__ vT, float* __restrict__ attn,
                f16* __restrict__ ctx) {
    const int bid = blockIdx.x;
    const int t = threadIdx.x;

    const int g7 = bid / 7, l7 = bid - g7 * 7;
    int aid;
    if (l7 < 4) {
        aid = g7 * 4 + l7;                          // [0,1024)
    } else {
        fill_rows32(attn, 40960 + (g7 * 3 + (l7 - 4)) * 32, t);  // fid [0,768)
        return;
    }

    __shared__ f16 sK[192 * 72];     // overlaid by sP (64*200 <= 192*72) after QK
    __shared__ f16 sVT[64 * 200];    // vT rows: [d][k window], stride 200 (400 B)
    f16* sP = sK;

    const int w = t >> 6, l = t & 63, l15 = l & 15, quad = l >> 4;
    const int tile = aid & 31, h = (aid >> 5) & 15, b = aid >> 9;
    const int q0 = tile * 64;
    const int jbase = q0 - 64;

    // ---- P0a: Q A-fragments straight to registers (rows w*16+l15) ----
    const f16* qg2 = qb + ((size_t)(b * Sc + q0 + w * 16 + l15)) * Dc + h * HDc;
    const f16x8 aq0 = *(const f16x8*)&qg2[quad * 8];
    const f16x8 aq1 = *(const f16x8*)&qg2[32 + quad * 8];

    // ---- P0b: stage K window (192x64), vT window (64x192) ----
    #pragma unroll
    for (int it = 0; it < 6; ++it) {
        const int idx = it * 256 + t;          // 0..1535
        const int r = idx >> 3, c = (idx & 7) * 8;
        int j = jbase + r;
        j = (j < 0) ? 0 : (j > Sc - 1 ? Sc - 1 : j);
        const size_t goff = ((size_t)(b * Sc + j)) * Dc + h * HDc + c;
        *(uint4*)&sK[r * 72 + c] = *(const uint4*)&kb[goff];
    }
    // vT rows: dd = t>>2 (0..63), chunks of 8 f16 along the token window.
    {
        const f16* vrow = vT + ((size_t)((b * Hc + h) * HDc)) * Sc + jbase;
        const int dd = t >> 2;
        #pragma unroll
        for (int it = 0; it < 6; ++it) {
            const int ch = it * 4 + (t & 3);   // 0..23
            *(uint4*)&sVT[dd * 200 + ch * 8] = *(const uint4*)&vrow[(size_t)dd * Sc + ch * 8];
        }
    }
    __syncthreads();

    // ---- QK^T: S[64x192]; wave w owns rows [16w,16w+16) ----
    f32x4 s[12];
    #pragma unroll
    for (int nt = 0; nt < 12; ++nt) s[nt] = (f32x4){0.f, 0.f, 0.f, 0.f};
    #pragma unroll
    for (int nt = 0; nt < 12; ++nt) {
        const f16x8 bk0 = *(const f16x8*)&sK[(nt * 16 + l15) * 72 + quad * 8];
        s[nt] = __builtin_amdgcn_mfma_f32_16x16x32_f16(aq0, bk0, s[nt], 0, 0, 0);
    }
    #pragma unroll
    for (int nt = 0; nt < 12; ++nt) {
        const f16x8 bk1 = *(const f16x8*)&sK[(nt * 16 + l15) * 72 + 32 + quad * 8];
        s[nt] = __builtin_amdgcn_mfma_f32_16x16x32_f16(aq1, bk1, s[nt], 0, 0, 0);
    }

    // ---- in-register softmax; lane holds rows w*16+quad*4+r, cols nt*16+l15
    float invr[4];
    #pragma unroll
    for (int r = 0; r < 4; ++r) {
        const int row = w * 16 + quad * 4 + r;
        const int lo = (row > 64 - q0) ? row : (64 - q0);
        const int hi2 = (row + 128 < 2111 - q0) ? (row + 128) : (2111 - q0);
        float m = -1e30f;
        #pragma unroll
        for (int nt = 0; nt < 12; ++nt) {
            const int jrel = nt * 16 + l15;
            const float v = s[nt][r] * 0.125f;
            if (jrel >= lo && jrel <= hi2) m = fmaxf(m, v);
        }
        #pragma unroll
        for (int k = 1; k < 16; k <<= 1) m = fmaxf(m, __shfl_xor(m, k, 64));
        float sum = 0.f;
        #pragma unroll
        for (int nt = 0; nt < 12; ++nt) {
            const int jrel = nt * 16 + l15;
            const float v = s[nt][r] * 0.125f;
            const float e = (jrel >= lo && jrel <= hi2) ? __expf(v - m) : 0.f;
            s[nt][r] = e;
            sum += e;
        }
        #pragma unroll
        for (int k = 1; k < 16; k <<= 1) sum += __shfl_xor(sum, k, 64);
        invr[r] = 1.f / sum;
    }
    __syncthreads();   // sK reads done -> safe to overlay sP

    // ---- P2: write P to LDS + aligned global window [a0,a1) (p=0 outside band)
    float* abase = attn + ((size_t)(b * Hc + h) * Sc) * Sc;
    #pragma unroll
    for (int r = 0; r < 4; ++r) {
        const int row = w * 16 + quad * 4 + r;
        const int i = q0 + row;
        const int lo0 = (i > 64) ? (i - 64) : 0;
        const int a0 = lo0 & ~31;
        const int hi0 = (i < Sc - 65) ? (i + 64) : (Sc - 1);
        int a1 = (hi0 + 32) & ~31; if (a1 > Sc) a1 = Sc;
        const int alo = a0 - jbase, ahi = a1 - jbase;
        #pragma unroll
        for (int nt = 0; nt < 12; ++nt) {
            const int jrel = nt * 16 + l15;
            const float p = s[nt][r] * invr[r];
            sP[row * 200 + jrel] = (f16)p;
            if (jrel >= alo && jrel < ahi)
                abase[(size_t)i * Sc + (jbase + jrel)] = p;
        }
    }
    __syncthreads();

    // ---- P3: ctx[64x64] = P[64x192] @ V[192x64], V from sVT via b128 ----
    f32x4 o[4];
    #pragma unroll
    for (int dt = 0; dt < 4; ++dt) o[dt] = (f32x4){0.f, 0.f, 0.f, 0.f};
    #pragma unroll
    for (int ks = 0; ks < 6; ++ks) {
        const f16x8 ap = *(const f16x8*)&sP[(w * 16 + l15) * 200 + ks * 32 + quad * 8];
        #pragma unroll
        for (int dt = 0; dt < 4; ++dt) {
            const f16x8 bv = *(const f16x8*)&sVT[(dt * 16 + l15) * 200 + ks * 32 + quad * 8];
            o[dt] = __builtin_amdgcn_mfma_f32_16x16x32_f16(ap, bv, o[dt], 0, 0, 0);
        }
    }
    f16* cg = ctx + ((size_t)(b * Sc + q0)) * Dc + h * HDc;
    #pragma unroll
    for (int dt = 0; dt < 4; ++dt)
        #pragma unroll
        for (int r = 0; r < 4; ++r) {
            const int row = w * 16 + quad * 4 + r;
            cg[(size_t)row * Dc + dt * 16 + l15] = (f16)o[dt][r];
        }
}

// ---------------------------------------------------------------------------
// MEASUREMENT ROUND 2 (resubmitted after infra failure): identical to R7
// except the QKV+fill kernel is launched TWICE (idempotent).
// dur_us - 644.6 = T_QKV exactly.
// Decision rule: >=75 -> port QKV to 256^2 8-phase; 55-75 -> BK=64;
// <55 -> QKV at floor -> declare roofline with the full budget.
// ---------------------------------------------------------------------------
extern "C" void kernel_launch(void* const* d_in, const int* in_sizes, int n_in,
                              void* d_out, int out_size, void* d_ws, size_t ws_size,
                              hipStream_t stream) {
    const float* x  = (const float*)d_in[0];
    const float* Wq = (const float*)d_in[1];
    const float* bq = (const float*)d_in[2];
    const float* Wk = (const float*)d_in[3];
    const float* bk = (const float*)d_in[4];
    const float* Wv = (const float*)d_in[5];
    const float* bv = (const float*)d_in[6];
    const float* Wo = (const float*)d_in[7];
    const float* bo = (const float*)d_in[8];

    float* out  = (float*)d_out;
    float* attn = out + PROJ;

    char* ws = (char*)d_ws;
    f16* Wcat  = (f16*)ws;                 // [4][1024][1024] fp16 = 8 MB
    f16* x_f16 = (f16*)(ws + (size_t)8  * 1024 * 1024);
    f16* q_f16 = (f16*)(ws + (size_t)16 * 1024 * 1024);
    f16* k_f16 = (f16*)(ws + (size_t)24 * 1024 * 1024);
    f16* c_f16 = (f16*)(ws + (size_t)40 * 1024 * 1024);
    // transposed V [2048 d-rows][2048 tokens] fp16 with 512 B guards each side
    f16* vT    = (f16*)(ws + (size_t)48 * 1024 * 1024 + 512);

    pack_all<<<dim3(8193), dim3(256), 0, stream>>>(x, Wq, Wk, Wv, Wo, x_f16, Wcat, vT);

    // QKV GEMM + fill — launched twice for the T_QKV measurement
    gemm_mega<f16, true><<<dim3(2048), dim3(256), 0, stream>>>(
        x_f16, Wcat, bq, bk, bv, q_f16, k_f16, vT, attn, 24);
    gemm_mega<f16, true><<<dim3(2048), dim3(256), 0, stream>>>(
        x_f16, Wcat, bq, bk, bv, q_f16, k_f16, vT, attn, 24);

    // attention (1024 blocks) + fill rows [40960,65536) (768 blocks)
    attn_fused<<<dim3(1792), dim3(256), 0, stream>>>(
        q_f16, k_f16, vT, attn, c_f16);

    // O projection: BM=64 tiles, 512 blocks, 2 blocks/CU
    gemm_o64<<<dim3(512), dim3(256), 0, stream>>>(
        c_f16, Wcat + 3 * WN, bo, out);
}

// Round 10
// 642.799 us; speedup vs baseline: 1.1802x; 1.1802x over previous
//
#include <hip/hip_runtime.h>
#include <math.h>
#include <stdint.h>

typedef _Float16 f16;
typedef f16   f16x8 __attribute__((ext_vector_type(8)));
typedef f16   f16x4 __attribute__((ext_vector_type(4)));
typedef float f32x4 __attribute__((ext_vector_type(4)));

constexpr int Bc = 2, Sc = 2048, Dc = 1024, Hc = 16, HDc = 64;
constexpr size_t PROJ = (size_t)Bc * Sc * Dc;     // 4,194,304
constexpr size_t WN   = (size_t)Dc * Dc;          // 1,048,576

// async 16B global->LDS (wave-uniform LDS base + lane*16 layout required)
__device__ __forceinline__ void gload_lds16(const void* g, void* l) {
    unsigned int off = (unsigned int)(uintptr_t)l;
    auto lp = (__attribute__((address_space(3))) unsigned int*)(uintptr_t)off;
    auto gp = (const __attribute__((address_space(1))) unsigned int*)(uintptr_t)g;
    __builtin_amdgcn_global_load_lds(gp, lp, 16, 0, 0);
}

// ---------------------------------------------------------------------------
// Band-complement zero fill: 32 rows/block; per row zero [0,a0) and [a1,2048)
// floats where a0/a1 are 32-float (128 B) aligned around the |i-j|<=64 band.
// ---------------------------------------------------------------------------
__device__ __forceinline__ void fill_rows32(float* __restrict__ attn, int grow0, int t) {
    const uint4 z = {0u, 0u, 0u, 0u};
    for (int rr = 0; rr < 32; ++rr) {
        const int gr = grow0 + rr;
        const int i = gr & (Sc - 1);
        const int lo = (i > 64) ? (i - 64) : 0;
        const int a0 = lo & ~31;
        const int hi = (i < Sc - 65) ? (i + 64) : (Sc - 1);
        int a1 = (hi + 32) & ~31; if (a1 > Sc) a1 = Sc;
        uint4* rowp = (uint4*)(attn + (size_t)gr * Sc);
        const int n4L = a0 >> 2;
        const int r0  = a1 >> 2;
        const int tot = n4L + (512 - r0);
        for (int idx = t; idx < tot; idx += 256) {
            const int p = (idx < n4L) ? idx : (r0 + idx - n4L);
            rowp[p] = z;
        }
    }
}

// ---------------------------------------------------------------------------
// fp32 -> fp16 pack: x (4096 blocks) + 4 weight tensors (4x1024 blocks)
// + 1 guard block zeroing the 512B margins around vT.
// ---------------------------------------------------------------------------
__global__ __launch_bounds__(256)
void pack_all(const float* __restrict__ x,
              const float* __restrict__ w0, const float* __restrict__ w1,
              const float* __restrict__ w2, const float* __restrict__ w3,
              f16* __restrict__ xd, f16* __restrict__ wd, f16* __restrict__ vT) {
    const int bid = blockIdx.x;
    if (bid == 8192) {
        const uint4 z = {0u, 0u, 0u, 0u};
        uint4* pre  = (uint4*)(vT - 256);                      // 512 B
        uint4* post = (uint4*)(vT + (size_t)4 * 1024 * 1024);  // 512 B
        const int t = threadIdx.x;
        if (t < 32) pre[t] = z;
        else if (t < 64) post[t - 32] = z;
        return;
    }
    const float* src;
    f16* dst;
    int off4;
    if (bid < 4096) {
        src = x; dst = xd; off4 = bid;
    } else {
        const int wi = (bid - 4096) >> 10;
        const int r  = (bid - 4096) & 1023;
        src = (wi == 0) ? w0 : (wi == 1) ? w1 : (wi == 2) ? w2 : w3;
        dst = wd + (size_t)wi * WN;
        off4 = r;
    }
    const int i = off4 * 256 + threadIdx.x;
    float4 f = ((const float4*)src)[i];
    f16x4 h = {(f16)f.x, (f16)f.y, (f16)f.z, (f16)f.w};
    ((f16x4*)dst)[i] = h;
}

// ---------------------------------------------------------------------------
// QKV GEMM (+ interleaved fill blocks, uniform 3:5 -> no all-fill tail).
// K-loop is now 2-phase double-buffered (T3 minimum recipe): STAGE(next)
// issued before compute, counted s_waitcnt vmcnt(4) + RAW s_barrier (NOT
// __syncthreads -- that would emit the full vmcnt(0) drain and kill the
// pipeline). LDS 2x16KB = 32KB -> still 3 blocks/CU.
// V (ten==2) stored TRANSPOSED: vT[(b*1024+col)][token&2047].
// ---------------------------------------------------------------------------
template <typename OutT, bool WITH_FILL>
__global__ __launch_bounds__(256, 3)
void gemm_mega(const f16* __restrict__ A, const f16* __restrict__ W,
               const float* __restrict__ b0, const float* __restrict__ b1,
               const float* __restrict__ b2,
               OutT* __restrict__ o0, OutT* __restrict__ o1, OutT* __restrict__ o2,
               float* __restrict__ fill, int n_ct) {
    constexpr int K = 1024, N = 1024;
    const int bid = blockIdx.x;
    const int t = threadIdx.x;

    int gid = bid;
    if (WITH_FILL) {
        const int g8 = bid >> 3, l8 = bid & 7;
        if (l8 < 3) {
            gid = g8 * 3 + l8;                    // [0,768)
        } else {
            fill_rows32(fill, (g8 * 5 + (l8 - 3)) * 32, t);   // fid [0,1280)
            return;
        }
    }

    __shared__ f16 sA[2][128 * 32];
    __shared__ f16 sB[2][128 * 32];

    const int w = t >> 6, l = t & 63, l15 = l & 15, quad = l >> 4;
    const int col_t = gid % n_ct, row_t = gid / n_ct;
    const int row0 = row_t * 128, col0 = col_t * 128;
    const int wr = w >> 1, wc = w & 1;

    f32x4 acc[4][4];
    #pragma unroll
    for (int i = 0; i < 4; ++i)
        #pragma unroll
        for (int j = 0; j < 4; ++j) acc[i][j] = (f32x4){0.f, 0.f, 0.f, 0.f};

    const int arow = t >> 2;          // 0..63
    const int koff = (t & 3) * 8;     // 8 f16 = 16B
    const f16* ga = A + (size_t)(row0 + arow) * K + koff;
    const f16* gb = W + (size_t)(col0 + arow) * K + koff;

    // stage one 32-wide K-tile into buffer `buf` (4 gload_lds / wave)
    auto STAGE = [&](int buf, int k0) {
        gload_lds16(ga + k0,                    &sA[buf][w * 512]);
        gload_lds16(ga + (size_t)64 * K + k0,   &sA[buf][2048 + w * 512]);
        gload_lds16(gb + k0,                    &sB[buf][w * 512]);
        gload_lds16(gb + (size_t)64 * K + k0,   &sB[buf][2048 + w * 512]);
    };

    STAGE(0, 0);
    int cur = 0;
    for (int k0 = 0; k0 < K; k0 += 32) {
        if (k0 + 32 < K) {
            STAGE(cur ^ 1, k0 + 32);                         // next tile in flight
            asm volatile("s_waitcnt vmcnt(4)" ::: "memory"); // cur tile landed
        } else {
            asm volatile("s_waitcnt vmcnt(0)" ::: "memory");
        }
        __builtin_amdgcn_s_barrier();                        // all waves' cur tile visible

        f16x8 af[4], bf[4];
        #pragma unroll
        for (int mi = 0; mi < 4; ++mi)
            af[mi] = *(const f16x8*)&sA[cur][(wr * 64 + mi * 16 + l15) * 32 + quad * 8];
        #pragma unroll
        for (int ni = 0; ni < 4; ++ni)
            bf[ni] = *(const f16x8*)&sB[cur][(wc * 64 + ni * 16 + l15) * 32 + quad * 8];
        #pragma unroll
        for (int mi = 0; mi < 4; ++mi)
            #pragma unroll
            for (int ni = 0; ni < 4; ++ni)
                acc[mi][ni] = __builtin_amdgcn_mfma_f32_16x16x32_f16(af[mi], bf[ni], acc[mi][ni], 0, 0, 0);

        asm volatile("s_waitcnt lgkmcnt(0)" ::: "memory");   // LDS reads drained
        __builtin_amdgcn_s_barrier();                        // safe to overwrite cur next iter
        cur ^= 1;
    }

    const int ten = col0 >> 10;                 // tile never straddles tensors
    const float* bias = (ten == 0) ? b0 : (ten == 1) ? b1 : b2;
    OutT* out = (ten == 0) ? o0 : (ten == 1) ? o1 : o2;
    const int nc0 = col0 & (N - 1);

    if constexpr (WITH_FILL) {
        if (ten == 2) {
            // transposed V store: lane holds tokens tok..tok+3 for column colv
            f16* vout = reinterpret_cast<f16*>(o2);
            #pragma unroll
            for (int mi = 0; mi < 4; ++mi)
                #pragma unroll
                for (int ni = 0; ni < 4; ++ni) {
                    const int tok  = row0 + wr * 64 + mi * 16 + quad * 4;
                    const int colv = nc0 + wc * 64 + ni * 16 + l15;
                    const float bvv = bias[colv];
                    f16x4 h4 = {(f16)(acc[mi][ni][0] + bvv), (f16)(acc[mi][ni][1] + bvv),
                                (f16)(acc[mi][ni][2] + bvv), (f16)(acc[mi][ni][3] + bvv)};
                    const int bb = tok >> 11;
                    *(f16x4*)&vout[((size_t)(bb * 1024 + colv)) * 2048 + (tok & 2047)] = h4;
                }
            return;
        }
    }

    #pragma unroll
    for (int mi = 0; mi < 4; ++mi)
        #pragma unroll
        for (int ni = 0; ni < 4; ++ni) {
            const int rbase = row0 + wr * 64 + mi * 16 + quad * 4;
            const int col = nc0 + wc * 64 + ni * 16 + l15;
            const float bv = bias[col];
            #pragma unroll
            for (int r = 0; r < 4; ++r)
                out[(size_t)(rbase + r) * N + col] = (OutT)(acc[mi][ni][r] + bv);
        }
}

// ---------------------------------------------------------------------------
// O-projection GEMM, BM=64 x BN=128, same 2-phase double-buffered K-loop
// (3 loads/iter -> vmcnt(3)).
// ---------------------------------------------------------------------------
__global__ __launch_bounds__(256, 3)
void gemm_o64(const f16* __restrict__ A, const f16* __restrict__ W,
              const float* __restrict__ bias, float* __restrict__ out) {
    constexpr int K = 1024, N = 1024;
    const int t = threadIdx.x;
    const int gid = blockIdx.x;

    __shared__ f16 sA[2][64 * 32];
    __shared__ f16 sB[2][128 * 32];

    const int w = t >> 6, l = t & 63, l15 = l & 15, quad = l >> 4;
    const int col_t = gid & 7, row_t = gid >> 3;
    const int row0 = row_t * 64, col0 = col_t * 128;

    f32x4 acc[4][2];
    #pragma unroll
    for (int i = 0; i < 4; ++i)
        #pragma unroll
        for (int j = 0; j < 2; ++j) acc[i][j] = (f32x4){0.f, 0.f, 0.f, 0.f};

    const int arow = t >> 2;          // 0..63
    const int koff = (t & 3) * 8;
    const f16* ga = A + (size_t)(row0 + arow) * K + koff;
    const f16* gb = W + (size_t)(col0 + arow) * K + koff;

    auto STAGE = [&](int buf, int k0) {
        gload_lds16(ga + k0,                  &sA[buf][w * 512]);
        gload_lds16(gb + k0,                  &sB[buf][w * 512]);
        gload_lds16(gb + (size_t)64 * K + k0, &sB[buf][2048 + w * 512]);
    };

    STAGE(0, 0);
    int cur = 0;
    for (int k0 = 0; k0 < K; k0 += 32) {
        if (k0 + 32 < K) {
            STAGE(cur ^ 1, k0 + 32);
            asm volatile("s_waitcnt vmcnt(3)" ::: "memory");
        } else {
            asm volatile("s_waitcnt vmcnt(0)" ::: "memory");
        }
        __builtin_amdgcn_s_barrier();

        f16x8 af[4], bf[2];
        #pragma unroll
        for (int mi = 0; mi < 4; ++mi)
            af[mi] = *(const f16x8*)&sA[cur][(mi * 16 + l15) * 32 + quad * 8];
        #pragma unroll
        for (int ni = 0; ni < 2; ++ni)
            bf[ni] = *(const f16x8*)&sB[cur][(w * 32 + ni * 16 + l15) * 32 + quad * 8];
        #pragma unroll
        for (int mi = 0; mi < 4; ++mi)
            #pragma unroll
            for (int ni = 0; ni < 2; ++ni)
                acc[mi][ni] = __builtin_amdgcn_mfma_f32_16x16x32_f16(af[mi], bf[ni], acc[mi][ni], 0, 0, 0);

        asm volatile("s_waitcnt lgkmcnt(0)" ::: "memory");
        __builtin_amdgcn_s_barrier();
        cur ^= 1;
    }

    #pragma unroll
    for (int mi = 0; mi < 4; ++mi)
        #pragma unroll
        for (int ni = 0; ni < 2; ++ni) {
            const int rbase = row0 + mi * 16 + quad * 4;
            const int col = col0 + w * 32 + ni * 16 + l15;
            const float bv = bias[col];
            #pragma unroll
            for (int r = 0; r < 4; ++r)
                out[(size_t)(rbase + r) * N + col] = acc[mi][ni][r] + bv;
        }
}

// ---------------------------------------------------------------------------
// Fused band attention (+ interleaved fill blocks, uniform 4:3 in groups of 7).
// Q in registers; K/vT staged in LDS (52 KB -> 3 blocks/CU). Unchanged.
// ---------------------------------------------------------------------------
__global__ __launch_bounds__(256, 3)
void attn_fused(const f16* __restrict__ qb, const f16* __restrict__ kb,
                const f16* __restrict__ vT, float* __restrict__ attn,
                f16* __restrict__ ctx) {
    const int bid = blockIdx.x;
    const int t = threadIdx.x;

    const int g7 = bid / 7, l7 = bid - g7 * 7;
    int aid;
    if (l7 < 4) {
        aid = g7 * 4 + l7;                          // [0,1024)
    } else {
        fill_rows32(attn, 40960 + (g7 * 3 + (l7 - 4)) * 32, t);  // fid [0,768)
        return;
    }

    __shared__ f16 sK[192 * 72];     // overlaid by sP (64*200 <= 192*72) after QK
    __shared__ f16 sVT[64 * 200];    // vT rows: [d][k window], stride 200 (400 B)
    f16* sP = sK;

    const int w = t >> 6, l = t & 63, l15 = l & 15, quad = l >> 4;
    const int tile = aid & 31, h = (aid >> 5) & 15, b = aid >> 9;
    const int q0 = tile * 64;
    const int jbase = q0 - 64;

    // ---- P0a: Q A-fragments straight to registers (rows w*16+l15) ----
    const f16* qg2 = qb + ((size_t)(b * Sc + q0 + w * 16 + l15)) * Dc + h * HDc;
    const f16x8 aq0 = *(const f16x8*)&qg2[quad * 8];
    const f16x8 aq1 = *(const f16x8*)&qg2[32 + quad * 8];

    // ---- P0b: stage K window (192x64), vT window (64x192) ----
    #pragma unroll
    for (int it = 0; it < 6; ++it) {
        const int idx = it * 256 + t;          // 0..1535
        const int r = idx >> 3, c = (idx & 7) * 8;
        int j = jbase + r;
        j = (j < 0) ? 0 : (j > Sc - 1 ? Sc - 1 : j);
        const size_t goff = ((size_t)(b * Sc + j)) * Dc + h * HDc + c;
        *(uint4*)&sK[r * 72 + c] = *(const uint4*)&kb[goff];
    }
    // vT rows: dd = t>>2 (0..63), chunks of 8 f16 along the token window.
    {
        const f16* vrow = vT + ((size_t)((b * Hc + h) * HDc)) * Sc + jbase;
        const int dd = t >> 2;
        #pragma unroll
        for (int it = 0; it < 6; ++it) {
            const int ch = it * 4 + (t & 3);   // 0..23
            *(uint4*)&sVT[dd * 200 + ch * 8] = *(const uint4*)&vrow[(size_t)dd * Sc + ch * 8];
        }
    }
    __syncthreads();

    // ---- QK^T: S[64x192]; wave w owns rows [16w,16w+16) ----
    f32x4 s[12];
    #pragma unroll
    for (int nt = 0; nt < 12; ++nt) s[nt] = (f32x4){0.f, 0.f, 0.f, 0.f};
    #pragma unroll
    for (int nt = 0; nt < 12; ++nt) {
        const f16x8 bk0 = *(const f16x8*)&sK[(nt * 16 + l15) * 72 + quad * 8];
        s[nt] = __builtin_amdgcn_mfma_f32_16x16x32_f16(aq0, bk0, s[nt], 0, 0, 0);
    }
    #pragma unroll
    for (int nt = 0; nt < 12; ++nt) {
        const f16x8 bk1 = *(const f16x8*)&sK[(nt * 16 + l15) * 72 + 32 + quad * 8];
        s[nt] = __builtin_amdgcn_mfma_f32_16x16x32_f16(aq1, bk1, s[nt], 0, 0, 0);
    }

    // ---- in-register softmax; lane holds rows w*16+quad*4+r, cols nt*16+l15
    float invr[4];
    #pragma unroll
    for (int r = 0; r < 4; ++r) {
        const int row = w * 16 + quad * 4 + r;
        const int lo = (row > 64 - q0) ? row : (64 - q0);
        const int hi2 = (row + 128 < 2111 - q0) ? (row + 128) : (2111 - q0);
        float m = -1e30f;
        #pragma unroll
        for (int nt = 0; nt < 12; ++nt) {
            const int jrel = nt * 16 + l15;
            const float v = s[nt][r] * 0.125f;
            if (jrel >= lo && jrel <= hi2) m = fmaxf(m, v);
        }
        #pragma unroll
        for (int k = 1; k < 16; k <<= 1) m = fmaxf(m, __shfl_xor(m, k, 64));
        float sum = 0.f;
        #pragma unroll
        for (int nt = 0; nt < 12; ++nt) {
            const int jrel = nt * 16 + l15;
            const float v = s[nt][r] * 0.125f;
            const float e = (jrel >= lo && jrel <= hi2) ? __expf(v - m) : 0.f;
            s[nt][r] = e;
            sum += e;
        }
        #pragma unroll
        for (int k = 1; k < 16; k <<= 1) sum += __shfl_xor(sum, k, 64);
        invr[r] = 1.f / sum;
    }
    __syncthreads();   // sK reads done -> safe to overlay sP

    // ---- P2: write P to LDS + aligned global window [a0,a1) (p=0 outside band)
    float* abase = attn + ((size_t)(b * Hc + h) * Sc) * Sc;
    #pragma unroll
    for (int r = 0; r < 4; ++r) {
        const int row = w * 16 + quad * 4 + r;
        const int i = q0 + row;
        const int lo0 = (i > 64) ? (i - 64) : 0;
        const int a0 = lo0 & ~31;
        const int hi0 = (i < Sc - 65) ? (i + 64) : (Sc - 1);
        int a1 = (hi0 + 32) & ~31; if (a1 > Sc) a1 = Sc;
        const int alo = a0 - jbase, ahi = a1 - jbase;
        #pragma unroll
        for (int nt = 0; nt < 12; ++nt) {
            const int jrel = nt * 16 + l15;
            const float p = s[nt][r] * invr[r];
            sP[row * 200 + jrel] = (f16)p;
            if (jrel >= alo && jrel < ahi)
                abase[(size_t)i * Sc + (jbase + jrel)] = p;
        }
    }
    __syncthreads();

    // ---- P3: ctx[64x64] = P[64x192] @ V[192x64], V from sVT via b128 ----
    f32x4 o[4];
    #pragma unroll
    for (int dt = 0; dt < 4; ++dt) o[dt] = (f32x4){0.f, 0.f, 0.f, 0.f};
    #pragma unroll
    for (int ks = 0; ks < 6; ++ks) {
        const f16x8 ap = *(const f16x8*)&sP[(w * 16 + l15) * 200 + ks * 32 + quad * 8];
        #pragma unroll
        for (int dt = 0; dt < 4; ++dt) {
            const f16x8 bv = *(const f16x8*)&sVT[(dt * 16 + l15) * 200 + ks * 32 + quad * 8];
            o[dt] = __builtin_amdgcn_mfma_f32_16x16x32_f16(ap, bv, o[dt], 0, 0, 0);
        }
    }
    f16* cg = ctx + ((size_t)(b * Sc + q0)) * Dc + h * HDc;
    #pragma unroll
    for (int dt = 0; dt < 4; ++dt)
        #pragma unroll
        for (int r = 0; r < 4; ++r) {
            const int row = w * 16 + quad * 4 + r;
            cg[(size_t)row * Dc + dt * 16 + l15] = (f16)o[dt][r];
        }
}

// ---------------------------------------------------------------------------
extern "C" void kernel_launch(void* const* d_in, const int* in_sizes, int n_in,
                              void* d_out, int out_size, void* d_ws, size_t ws_size,
                              hipStream_t stream) {
    const float* x  = (const float*)d_in[0];
    const float* Wq = (const float*)d_in[1];
    const float* bq = (const float*)d_in[2];
    const float* Wk = (const float*)d_in[3];
    const float* bk = (const float*)d_in[4];
    const float* Wv = (const float*)d_in[5];
    const float* bv = (const float*)d_in[6];
    const float* Wo = (const float*)d_in[7];
    const float* bo = (const float*)d_in[8];

    float* out  = (float*)d_out;
    float* attn = out + PROJ;

    char* ws = (char*)d_ws;
    f16* Wcat  = (f16*)ws;                 // [4][1024][1024] fp16 = 8 MB
    f16* x_f16 = (f16*)(ws + (size_t)8  * 1024 * 1024);
    f16* q_f16 = (f16*)(ws + (size_t)16 * 1024 * 1024);
    f16* k_f16 = (f16*)(ws + (size_t)24 * 1024 * 1024);
    f16* c_f16 = (f16*)(ws + (size_t)40 * 1024 * 1024);
    // transposed V [2048 d-rows][2048 tokens] fp16 with 512 B guards each side
    f16* vT    = (f16*)(ws + (size_t)48 * 1024 * 1024 + 512);

    pack_all<<<dim3(8193), dim3(256), 0, stream>>>(x, Wq, Wk, Wv, Wo, x_f16, Wcat, vT);

    // fused QKV GEMM (768 blocks, 2-phase pipelined) + fill rows [0,40960)
    gemm_mega<f16, true><<<dim3(2048), dim3(256), 0, stream>>>(
        x_f16, Wcat, bq, bk, bv, q_f16, k_f16, vT, attn, 24);

    // attention (1024 blocks) + fill rows [40960,65536) (768 blocks)
    attn_fused<<<dim3(1792), dim3(256), 0, stream>>>(
        q_f16, k_f16, vT, attn, c_f16);

    // O projection: BM=64 tiles, 512 blocks, 2-phase pipelined
    gemm_o64<<<dim3(512), dim3(256), 0, stream>>>(
        c_f16, Wcat + 3 * WN, bo, out);
}

// Round 12
// 631.346 us; speedup vs baseline: 1.2016x; 1.0181x over previous
//
#include <hip/hip_runtime.h>
#include <math.h>
#include <stdint.h>

typedef _Float16 f16;
typedef f16   f16x8 __attribute__((ext_vector_type(8)));
typedef f16   f16x4 __attribute__((ext_vector_type(4)));
typedef float f32x4 __attribute__((ext_vector_type(4)));
typedef unsigned int u32x4 __attribute__((ext_vector_type(4)));   // native vector for NT stores

// async 16B global->LDS (wave-uniform LDS base + lane*16 layout required)
__device__ __forceinline__ void gload_lds16(const void* g, void* l) {
    unsigned int off = (unsigned int)(uintptr_t)l;
    auto lp = (__attribute__((address_space(3))) unsigned int*)(uintptr_t)off;
    auto gp = (const __attribute__((address_space(1))) unsigned int*)(uintptr_t)g;
    __builtin_amdgcn_global_load_lds(gp, lp, 16, 0, 0);
}

constexpr int Bc = 2, Sc = 2048, Dc = 1024, Hc = 16, HDc = 64;
constexpr size_t PROJ = (size_t)Bc * Sc * Dc;     // 4,194,304
constexpr size_t WN   = (size_t)Dc * Dc;          // 1,048,576

// ---------------------------------------------------------------------------
// Band-complement zero fill: 32 rows/block; per row zero [0,a0) and [a1,2048)
// floats. NON-TEMPORAL stores (native u32x4 -- HIP uint4 is a class type the
// builtin rejects): these ~490 MB of zeros are never re-read; cached stores
// write-allocate in L2, throttling write BW and evicting the GEMM working
// set (theory for the 2.9 vs 6.3 TB/s effective-write gap).
// ---------------------------------------------------------------------------
__device__ __forceinline__ void fill_rows32(float* __restrict__ attn, int grow0, int t) {
    const u32x4 z = {0u, 0u, 0u, 0u};
    for (int rr = 0; rr < 32; ++rr) {
        const int gr = grow0 + rr;
        const int i = gr & (Sc - 1);
        const int lo = (i > 64) ? (i - 64) : 0;
        const int a0 = lo & ~31;
        const int hi = (i < Sc - 65) ? (i + 64) : (Sc - 1);
        int a1 = (hi + 32) & ~31; if (a1 > Sc) a1 = Sc;
        u32x4* rowp = (u32x4*)(attn + (size_t)gr * Sc);
        const int n4L = a0 >> 2;
        const int r0  = a1 >> 2;
        const int tot = n4L + (512 - r0);
        for (int idx = t; idx < tot; idx += 256) {
            const int p = (idx < n4L) ? idx : (r0 + idx - n4L);
            __builtin_nontemporal_store(z, &rowp[p]);
        }
    }
}

// ---------------------------------------------------------------------------
// fp32 -> fp16 pack: x (4096 blocks) + 4 weight tensors (4x1024 blocks)
// + 1 guard block zeroing the 512B margins around vT.
// ---------------------------------------------------------------------------
__global__ __launch_bounds__(256)
void pack_all(const float* __restrict__ x,
              const float* __restrict__ w0, const float* __restrict__ w1,
              const float* __restrict__ w2, const float* __restrict__ w3,
              f16* __restrict__ xd, f16* __restrict__ wd, f16* __restrict__ vT) {
    const int bid = blockIdx.x;
    if (bid == 8192) {
        const uint4 z = {0u, 0u, 0u, 0u};
        uint4* pre  = (uint4*)(vT - 256);                      // 512 B
        uint4* post = (uint4*)(vT + (size_t)4 * 1024 * 1024);  // 512 B
        const int t = threadIdx.x;
        if (t < 32) pre[t] = z;
        else if (t < 64) post[t - 32] = z;
        return;
    }
    const float* src;
    f16* dst;
    int off4;
    if (bid < 4096) {
        src = x; dst = xd; off4 = bid;
    } else {
        const int wi = (bid - 4096) >> 10;
        const int r  = (bid - 4096) & 1023;
        src = (wi == 0) ? w0 : (wi == 1) ? w1 : (wi == 2) ? w2 : w3;
        dst = wd + (size_t)wi * WN;
        off4 = r;
    }
    const int i = off4 * 256 + threadIdx.x;
    float4 f = ((const float4*)src)[i];
    f16x4 h = {(f16)f.x, (f16)f.y, (f16)f.z, (f16)f.w};
    ((f16x4*)dst)[i] = h;
}

// ---------------------------------------------------------------------------
// QKV GEMM (+ interleaved fill blocks, uniform 3:5). 2-phase double-buffered
// K-loop (counted vmcnt + raw barriers). V (ten==2) stored TRANSPOSED.
// ---------------------------------------------------------------------------
template <typename OutT, bool WITH_FILL>
__global__ __launch_bounds__(256, 3)
void gemm_mega(const f16* __restrict__ A, const f16* __restrict__ W,
               const float* __restrict__ b0, const float* __restrict__ b1,
               const float* __restrict__ b2,
               OutT* __restrict__ o0, OutT* __restrict__ o1, OutT* __restrict__ o2,
               float* __restrict__ fill, int n_ct) {
    constexpr int K = 1024, N = 1024;
    const int bid = blockIdx.x;
    const int t = threadIdx.x;

    int gid = bid;
    if (WITH_FILL) {
        const int g8 = bid >> 3, l8 = bid & 7;
        if (l8 < 3) {
            gid = g8 * 3 + l8;                    // [0,768)
        } else {
            fill_rows32(fill, (g8 * 5 + (l8 - 3)) * 32, t);   // fid [0,1280)
            return;
        }
    }

    __shared__ f16 sA[2][128 * 32];
    __shared__ f16 sB[2][128 * 32];

    const int w = t >> 6, l = t & 63, l15 = l & 15, quad = l >> 4;
    const int col_t = gid % n_ct, row_t = gid / n_ct;
    const int row0 = row_t * 128, col0 = col_t * 128;
    const int wr = w >> 1, wc = w & 1;

    f32x4 acc[4][4];
    #pragma unroll
    for (int i = 0; i < 4; ++i)
        #pragma unroll
        for (int j = 0; j < 4; ++j) acc[i][j] = (f32x4){0.f, 0.f, 0.f, 0.f};

    const int arow = t >> 2;          // 0..63
    const int koff = (t & 3) * 8;     // 8 f16 = 16B
    const f16* ga = A + (size_t)(row0 + arow) * K + koff;
    const f16* gb = W + (size_t)(col0 + arow) * K + koff;

    auto STAGE = [&](int buf, int k0) {
        gload_lds16(ga + k0,                    &sA[buf][w * 512]);
        gload_lds16(ga + (size_t)64 * K + k0,   &sA[buf][2048 + w * 512]);
        gload_lds16(gb + k0,                    &sB[buf][w * 512]);
        gload_lds16(gb + (size_t)64 * K + k0,   &sB[buf][2048 + w * 512]);
    };

    STAGE(0, 0);
    int cur = 0;
    for (int k0 = 0; k0 < K; k0 += 32) {
        if (k0 + 32 < K) {
            STAGE(cur ^ 1, k0 + 32);                         // next tile in flight
            asm volatile("s_waitcnt vmcnt(4)" ::: "memory"); // cur tile landed
        } else {
            asm volatile("s_waitcnt vmcnt(0)" ::: "memory");
        }
        __builtin_amdgcn_s_barrier();                        // cur tile visible

        f16x8 af[4], bf[4];
        #pragma unroll
        for (int mi = 0; mi < 4; ++mi)
            af[mi] = *(const f16x8*)&sA[cur][(wr * 64 + mi * 16 + l15) * 32 + quad * 8];
        #pragma unroll
        for (int ni = 0; ni < 4; ++ni)
            bf[ni] = *(const f16x8*)&sB[cur][(wc * 64 + ni * 16 + l15) * 32 + quad * 8];
        #pragma unroll
        for (int mi = 0; mi < 4; ++mi)
            #pragma unroll
            for (int ni = 0; ni < 4; ++ni)
                acc[mi][ni] = __builtin_amdgcn_mfma_f32_16x16x32_f16(af[mi], bf[ni], acc[mi][ni], 0, 0, 0);

        asm volatile("s_waitcnt lgkmcnt(0)" ::: "memory");   // LDS reads drained
        __builtin_amdgcn_s_barrier();                        // safe to overwrite next iter
        cur ^= 1;
    }

    const int ten = col0 >> 10;                 // tile never straddles tensors
    const float* bias = (ten == 0) ? b0 : (ten == 1) ? b1 : b2;
    OutT* out = (ten == 0) ? o0 : (ten == 1) ? o1 : o2;
    const int nc0 = col0 & (N - 1);

    if constexpr (WITH_FILL) {
        if (ten == 2) {
            // transposed V store: lane holds tokens tok..tok+3 for column colv
            f16* vout = reinterpret_cast<f16*>(o2);
            #pragma unroll
            for (int mi = 0; mi < 4; ++mi)
                #pragma unroll
                for (int ni = 0; ni < 4; ++ni) {
                    const int tok  = row0 + wr * 64 + mi * 16 + quad * 4;
                    const int colv = nc0 + wc * 64 + ni * 16 + l15;
                    const float bvv = bias[colv];
                    f16x4 h4 = {(f16)(acc[mi][ni][0] + bvv), (f16)(acc[mi][ni][1] + bvv),
                                (f16)(acc[mi][ni][2] + bvv), (f16)(acc[mi][ni][3] + bvv)};
                    const int bb = tok >> 11;
                    *(f16x4*)&vout[((size_t)(bb * 1024 + colv)) * 2048 + (tok & 2047)] = h4;
                }
            return;
        }
    }

    #pragma unroll
    for (int mi = 0; mi < 4; ++mi)
        #pragma unroll
        for (int ni = 0; ni < 4; ++ni) {
            const int rbase = row0 + wr * 64 + mi * 16 + quad * 4;
            const int col = nc0 + wc * 64 + ni * 16 + l15;
            const float bv = bias[col];
            #pragma unroll
            for (int r = 0; r < 4; ++r)
                out[(size_t)(rbase + r) * N + col] = (OutT)(acc[mi][ni][r] + bv);
        }
}

// ---------------------------------------------------------------------------
// O-projection GEMM, BM=64 x BN=128, 2-phase double-buffered K-loop.
// ---------------------------------------------------------------------------
__global__ __launch_bounds__(256, 3)
void gemm_o64(const f16* __restrict__ A, const f16* __restrict__ W,
              const float* __restrict__ bias, float* __restrict__ out) {
    constexpr int K = 1024, N = 1024;
    const int t = threadIdx.x;
    const int gid = blockIdx.x;

    __shared__ f16 sA[2][64 * 32];
    __shared__ f16 sB[2][128 * 32];

    const int w = t >> 6, l = t & 63, l15 = l & 15, quad = l >> 4;
    const int col_t = gid & 7, row_t = gid >> 3;
    const int row0 = row_t * 64, col0 = col_t * 128;

    f32x4 acc[4][2];
    #pragma unroll
    for (int i = 0; i < 4; ++i)
        #pragma unroll
        for (int j = 0; j < 2; ++j) acc[i][j] = (f32x4){0.f, 0.f, 0.f, 0.f};

    const int arow = t >> 2;          // 0..63
    const int koff = (t & 3) * 8;
    const f16* ga = A + (size_t)(row0 + arow) * K + koff;
    const f16* gb = W + (size_t)(col0 + arow) * K + koff;

    auto STAGE = [&](int buf, int k0) {
        gload_lds16(ga + k0,                  &sA[buf][w * 512]);
        gload_lds16(gb + k0,                  &sB[buf][w * 512]);
        gload_lds16(gb + (size_t)64 * K + k0, &sB[buf][2048 + w * 512]);
    };

    STAGE(0, 0);
    int cur = 0;
    for (int k0 = 0; k0 < K; k0 += 32) {
        if (k0 + 32 < K) {
            STAGE(cur ^ 1, k0 + 32);
            asm volatile("s_waitcnt vmcnt(3)" ::: "memory");
        } else {
            asm volatile("s_waitcnt vmcnt(0)" ::: "memory");
        }
        __builtin_amdgcn_s_barrier();

        f16x8 af[4], bf[2];
        #pragma unroll
        for (int mi = 0; mi < 4; ++mi)
            af[mi] = *(const f16x8*)&sA[cur][(mi * 16 + l15) * 32 + quad * 8];
        #pragma unroll
        for (int ni = 0; ni < 2; ++ni)
            bf[ni] = *(const f16x8*)&sB[cur][(w * 32 + ni * 16 + l15) * 32 + quad * 8];
        #pragma unroll
        for (int mi = 0; mi < 4; ++mi)
            #pragma unroll
            for (int ni = 0; ni < 2; ++ni)
                acc[mi][ni] = __builtin_amdgcn_mfma_f32_16x16x32_f16(af[mi], bf[ni], acc[mi][ni], 0, 0, 0);

        asm volatile("s_waitcnt lgkmcnt(0)" ::: "memory");
        __builtin_amdgcn_s_barrier();
        cur ^= 1;
    }

    #pragma unroll
    for (int mi = 0; mi < 4; ++mi)
        #pragma unroll
        for (int ni = 0; ni < 2; ++ni) {
            const int rbase = row0 + mi * 16 + quad * 4;
            const int col = col0 + w * 32 + ni * 16 + l15;
            const float bv = bias[col];
            #pragma unroll
            for (int r = 0; r < 4; ++r)
                out[(size_t)(rbase + r) * N + col] = acc[mi][ni][r] + bv;
        }
}

// ---------------------------------------------------------------------------
// Fused band attention (+ interleaved fill blocks, uniform 4:3 in groups of 7).
// Q in registers; K/vT staged in LDS. Band writes to the attn buffer are
// NON-TEMPORAL (written once, never re-read by us).
// ---------------------------------------------------------------------------
__global__ __launch_bounds__(256, 3)
void attn_fused(const f16* __restrict__ qb, const f16* __restrict__ kb,
                const f16* __restrict__ vT, float* __restrict__ attn,
                f16* __restrict__ ctx) {
    const int bid = blockIdx.x;
    const int t = threadIdx.x;

    const int g7 = bid / 7, l7 = bid - g7 * 7;
    int aid;
    if (l7 < 4) {
        aid = g7 * 4 + l7;                          // [0,1024)
    } else {
        fill_rows32(attn, 40960 + (g7 * 3 + (l7 - 4)) * 32, t);  // fid [0,768)
        return;
    }

    __shared__ f16 sK[192 * 72];     // overlaid by sP (64*200 <= 192*72) after QK
    __shared__ f16 sVT[64 * 200];    // vT rows: [d][k window], stride 200 (400 B)
    f16* sP = sK;

    const int w = t >> 6, l = t & 63, l15 = l & 15, quad = l >> 4;
    const int tile = aid & 31, h = (aid >> 5) & 15, b = aid >> 9;
    const int q0 = tile * 64;
    const int jbase = q0 - 64;

    // ---- P0a: Q A-fragments straight to registers (rows w*16+l15) ----
    const f16* qg2 = qb + ((size_t)(b * Sc + q0 + w * 16 + l15)) * Dc + h * HDc;
    const f16x8 aq0 = *(const f16x8*)&qg2[quad * 8];
    const f16x8 aq1 = *(const f16x8*)&qg2[32 + quad * 8];

    // ---- P0b: stage K window (192x64), vT window (64x192) ----
    #pragma unroll
    for (int it = 0; it < 6; ++it) {
        const int idx = it * 256 + t;          // 0..1535
        const int r = idx >> 3, c = (idx & 7) * 8;
        int j = jbase + r;
        j = (j < 0) ? 0 : (j > Sc - 1 ? Sc - 1 : j);
        const size_t goff = ((size_t)(b * Sc + j)) * Dc + h * HDc + c;
        *(uint4*)&sK[r * 72 + c] = *(const uint4*)&kb[goff];
    }
    // vT rows: dd = t>>2 (0..63), chunks of 8 f16 along the token window.
    {
        const f16* vrow = vT + ((size_t)((b * Hc + h) * HDc)) * Sc + jbase;
        const int dd = t >> 2;
        #pragma unroll
        for (int it = 0; it < 6; ++it) {
            const int ch = it * 4 + (t & 3);   // 0..23
            *(uint4*)&sVT[dd * 200 + ch * 8] = *(const uint4*)&vrow[(size_t)dd * Sc + ch * 8];
        }
    }
    __syncthreads();

    // ---- QK^T: S[64x192]; wave w owns rows [16w,16w+16) ----
    f32x4 s[12];
    #pragma unroll
    for (int nt = 0; nt < 12; ++nt) s[nt] = (f32x4){0.f, 0.f, 0.f, 0.f};
    #pragma unroll
    for (int nt = 0; nt < 12; ++nt) {
        const f16x8 bk0 = *(const f16x8*)&sK[(nt * 16 + l15) * 72 + quad * 8];
        s[nt] = __builtin_amdgcn_mfma_f32_16x16x32_f16(aq0, bk0, s[nt], 0, 0, 0);
    }
    #pragma unroll
    for (int nt = 0; nt < 12; ++nt) {
        const f16x8 bk1 = *(const f16x8*)&sK[(nt * 16 + l15) * 72 + 32 + quad * 8];
        s[nt] = __builtin_amdgcn_mfma_f32_16x16x32_f16(aq1, bk1, s[nt], 0, 0, 0);
    }

    // ---- in-register softmax; lane holds rows w*16+quad*4+r, cols nt*16+l15
    float invr[4];
    #pragma unroll
    for (int r = 0; r < 4; ++r) {
        const int row = w * 16 + quad * 4 + r;
        const int lo = (row > 64 - q0) ? row : (64 - q0);
        const int hi2 = (row + 128 < 2111 - q0) ? (row + 128) : (2111 - q0);
        float m = -1e30f;
        #pragma unroll
        for (int nt = 0; nt < 12; ++nt) {
            const int jrel = nt * 16 + l15;
            const float v = s[nt][r] * 0.125f;
            if (jrel >= lo && jrel <= hi2) m = fmaxf(m, v);
        }
        #pragma unroll
        for (int k = 1; k < 16; k <<= 1) m = fmaxf(m, __shfl_xor(m, k, 64));
        float sum = 0.f;
        #pragma unroll
        for (int nt = 0; nt < 12; ++nt) {
            const int jrel = nt * 16 + l15;
            const float v = s[nt][r] * 0.125f;
            const float e = (jrel >= lo && jrel <= hi2) ? __expf(v - m) : 0.f;
            s[nt][r] = e;
            sum += e;
        }
        #pragma unroll
        for (int k = 1; k < 16; k <<= 1) sum += __shfl_xor(sum, k, 64);
        invr[r] = 1.f / sum;
    }
    __syncthreads();   // sK reads done -> safe to overlay sP

    // ---- P2: write P to LDS + aligned global window [a0,a1), NT stores ----
    float* abase = attn + ((size_t)(b * Hc + h) * Sc) * Sc;
    #pragma unroll
    for (int r = 0; r < 4; ++r) {
        const int row = w * 16 + quad * 4 + r;
        const int i = q0 + row;
        const int lo0 = (i > 64) ? (i - 64) : 0;
        const int a0 = lo0 & ~31;
        const int hi0 = (i < Sc - 65) ? (i + 64) : (Sc - 1);
        int a1 = (hi0 + 32) & ~31; if (a1 > Sc) a1 = Sc;
        const int alo = a0 - jbase, ahi = a1 - jbase;
        #pragma unroll
        for (int nt = 0; nt < 12; ++nt) {
            const int jrel = nt * 16 + l15;
            const float p = s[nt][r] * invr[r];
            sP[row * 200 + jrel] = (f16)p;
            if (jrel >= alo && jrel < ahi)
                __builtin_nontemporal_store(p, &abase[(size_t)i * Sc + (jbase + jrel)]);
        }
    }
    __syncthreads();

    // ---- P3: ctx[64x64] = P[64x192] @ V[192x64], V from sVT via b128 ----
    f32x4 o[4];
    #pragma unroll
    for (int dt = 0; dt < 4; ++dt) o[dt] = (f32x4){0.f, 0.f, 0.f, 0.f};
    #pragma unroll
    for (int ks = 0; ks < 6; ++ks) {
        const f16x8 ap = *(const f16x8*)&sP[(w * 16 + l15) * 200 + ks * 32 + quad * 8];
        #pragma unroll
        for (int dt = 0; dt < 4; ++dt) {
            const f16x8 bv = *(const f16x8*)&sVT[(dt * 16 + l15) * 200 + ks * 32 + quad * 8];
            o[dt] = __builtin_amdgcn_mfma_f32_16x16x32_f16(ap, bv, o[dt], 0, 0, 0);
        }
    }
    f16* cg = ctx + ((size_t)(b * Sc + q0)) * Dc + h * HDc;
    #pragma unroll
    for (int dt = 0; dt < 4; ++dt)
        #pragma unroll
        for (int r = 0; r < 4; ++r) {
            const int row = w * 16 + quad * 4 + r;
            cg[(size_t)row * Dc + dt * 16 + l15] = (f16)o[dt][r];
        }
}

// ---------------------------------------------------------------------------
extern "C" void kernel_launch(void* const* d_in, const int* in_sizes, int n_in,
                              void* d_out, int out_size, void* d_ws, size_t ws_size,
                              hipStream_t stream) {
    const float* x  = (const float*)d_in[0];
    const float* Wq = (const float*)d_in[1];
    const float* bq = (const float*)d_in[2];
    const float* Wk = (const float*)d_in[3];
    const float* bk = (const float*)d_in[4];
    const float* Wv = (const float*)d_in[5];
    const float* bv = (const float*)d_in[6];
    const float* Wo = (const float*)d_in[7];
    const float* bo = (const float*)d_in[8];

    float* out  = (float*)d_out;
    float* attn = out + PROJ;

    char* ws = (char*)d_ws;
    f16* Wcat  = (f16*)ws;                 // [4][1024][1024] fp16 = 8 MB
    f16* x_f16 = (f16*)(ws + (size_t)8  * 1024 * 1024);
    f16* q_f16 = (f16*)(ws + (size_t)16 * 1024 * 1024);
    f16* k_f16 = (f16*)(ws + (size_t)24 * 1024 * 1024);
    f16* c_f16 = (f16*)(ws + (size_t)40 * 1024 * 1024);
    // transposed V [2048 d-rows][2048 tokens] fp16 with 512 B guards each side
    f16* vT    = (f16*)(ws + (size_t)48 * 1024 * 1024 + 512);

    pack_all<<<dim3(8193), dim3(256), 0, stream>>>(x, Wq, Wk, Wv, Wo, x_f16, Wcat, vT);

    // fused QKV GEMM (768 blocks, pipelined) + NT fill rows [0,40960)
    gemm_mega<f16, true><<<dim3(2048), dim3(256), 0, stream>>>(
        x_f16, Wcat, bq, bk, bv, q_f16, k_f16, vT, attn, 24);

    // attention (1024 blocks) + NT fill rows [40960,65536) (768 blocks)
    attn_fused<<<dim3(1792), dim3(256), 0, stream>>>(
        q_f16, k_f16, vT, attn, c_f16);

    // O projection: BM=64 tiles, 512 blocks, pipelined
    gemm_o64<<<dim3(512), dim3(256), 0, stream>>>(
        c_f16, Wcat + 3 * WN, bo, out);
}

// Round 13
// 627.173 us; speedup vs baseline: 1.2096x; 1.0067x over previous
//
#include <hip/hip_runtime.h>
#include <math.h>
#include <stdint.h>

typedef _Float16 f16;
typedef f16   f16x8 __attribute__((ext_vector_type(8)));
typedef f16   f16x4 __attribute__((ext_vector_type(4)));
typedef float f32x4 __attribute__((ext_vector_type(4)));
typedef unsigned int u32x4 __attribute__((ext_vector_type(4)));   // native vector for NT stores

// async 16B global->LDS (wave-uniform LDS base + lane*16 layout required)
__device__ __forceinline__ void gload_lds16(const void* g, void* l) {
    unsigned int off = (unsigned int)(uintptr_t)l;
    auto lp = (__attribute__((address_space(3))) unsigned int*)(uintptr_t)off;
    auto gp = (const __attribute__((address_space(1))) unsigned int*)(uintptr_t)g;
    __builtin_amdgcn_global_load_lds(gp, lp, 16, 0, 0);
}

constexpr int Bc = 2, Sc = 2048, Dc = 1024, Hc = 16, HDc = 64;
constexpr size_t PROJ = (size_t)Bc * Sc * Dc;     // 4,194,304
constexpr size_t WN   = (size_t)Dc * Dc;          // 1,048,576

// ---------------------------------------------------------------------------
// Band-complement zero fill: 32 rows/block; NT stores (never re-read).
// ---------------------------------------------------------------------------
__device__ __forceinline__ void fill_rows32(float* __restrict__ attn, int grow0, int t) {
    const u32x4 z = {0u, 0u, 0u, 0u};
    for (int rr = 0; rr < 32; ++rr) {
        const int gr = grow0 + rr;
        const int i = gr & (Sc - 1);
        const int lo = (i > 64) ? (i - 64) : 0;
        const int a0 = lo & ~31;
        const int hi = (i < Sc - 65) ? (i + 64) : (Sc - 1);
        int a1 = (hi + 32) & ~31; if (a1 > Sc) a1 = Sc;
        u32x4* rowp = (u32x4*)(attn + (size_t)gr * Sc);
        const int n4L = a0 >> 2;
        const int r0  = a1 >> 2;
        const int tot = n4L + (512 - r0);
        for (int idx = t; idx < tot; idx += 256) {
            const int p = (idx < n4L) ? idx : (r0 + idx - n4L);
            __builtin_nontemporal_store(z, &rowp[p]);
        }
    }
}

// ---------------------------------------------------------------------------
// fp32 -> fp16 pack: x (4096 blocks) + 4 weight tensors (4x1024 blocks)
// + 1 guard block zeroing the 512B margins around vT.
// ---------------------------------------------------------------------------
__global__ __launch_bounds__(256)
void pack_all(const float* __restrict__ x,
              const float* __restrict__ w0, const float* __restrict__ w1,
              const float* __restrict__ w2, const float* __restrict__ w3,
              f16* __restrict__ xd, f16* __restrict__ wd, f16* __restrict__ vT) {
    const int bid = blockIdx.x;
    if (bid == 8192) {
        const uint4 z = {0u, 0u, 0u, 0u};
        uint4* pre  = (uint4*)(vT - 256);                      // 512 B
        uint4* post = (uint4*)(vT + (size_t)4 * 1024 * 1024);  // 512 B
        const int t = threadIdx.x;
        if (t < 32) pre[t] = z;
        else if (t < 64) post[t - 32] = z;
        return;
    }
    const float* src;
    f16* dst;
    int off4;
    if (bid < 4096) {
        src = x; dst = xd; off4 = bid;
    } else {
        const int wi = (bid - 4096) >> 10;
        const int r  = (bid - 4096) & 1023;
        src = (wi == 0) ? w0 : (wi == 1) ? w1 : (wi == 2) ? w2 : w3;
        dst = wd + (size_t)wi * WN;
        off4 = r;
    }
    const int i = off4 * 256 + threadIdx.x;
    float4 f = ((const float4*)src)[i];
    f16x4 h = {(f16)f.x, (f16)f.y, (f16)f.z, (f16)f.w};
    ((f16x4*)dst)[i] = h;
}

// ---------------------------------------------------------------------------
// QKV GEMM + fill, CLUSTERED layout: blocks [0,768) = GEMM (exactly 256 CUs
// x 3 blocks/CU -> full-density GEMM phase at m97-style co-scheduling);
// blocks [768,2048) = fill, flowing in as GEMM blocks retire (tail overlap).
// The 3:5 uniform interleave gave each CU only ~1.1 GEMM blocks -> GEMM ran
// far below full density while fill gained nothing (write pipe is chip-level).
// 2-phase double-buffered K-loop; V (ten==2) stored TRANSPOSED.
// ---------------------------------------------------------------------------
template <typename OutT, bool WITH_FILL>
__global__ __launch_bounds__(256, 3)
void gemm_mega(const f16* __restrict__ A, const f16* __restrict__ W,
               const float* __restrict__ b0, const float* __restrict__ b1,
               const float* __restrict__ b2,
               OutT* __restrict__ o0, OutT* __restrict__ o1, OutT* __restrict__ o2,
               float* __restrict__ fill, int n_ct) {
    constexpr int K = 1024, N = 1024;
    const int bid = blockIdx.x;
    const int t = threadIdx.x;

    int gid = bid;
    if (WITH_FILL) {
        if (bid >= 768) {
            fill_rows32(fill, (bid - 768) * 32, t);   // fid [0,1280)
            return;
        }
        // gid = bid in [0,768): GEMM-first clustering
    }

    __shared__ f16 sA[2][128 * 32];
    __shared__ f16 sB[2][128 * 32];

    const int w = t >> 6, l = t & 63, l15 = l & 15, quad = l >> 4;
    const int col_t = gid % n_ct, row_t = gid / n_ct;
    const int row0 = row_t * 128, col0 = col_t * 128;
    const int wr = w >> 1, wc = w & 1;

    f32x4 acc[4][4];
    #pragma unroll
    for (int i = 0; i < 4; ++i)
        #pragma unroll
        for (int j = 0; j < 4; ++j) acc[i][j] = (f32x4){0.f, 0.f, 0.f, 0.f};

    const int arow = t >> 2;          // 0..63
    const int koff = (t & 3) * 8;     // 8 f16 = 16B
    const f16* ga = A + (size_t)(row0 + arow) * K + koff;
    const f16* gb = W + (size_t)(col0 + arow) * K + koff;

    auto STAGE = [&](int buf, int k0) {
        gload_lds16(ga + k0,                    &sA[buf][w * 512]);
        gload_lds16(ga + (size_t)64 * K + k0,   &sA[buf][2048 + w * 512]);
        gload_lds16(gb + k0,                    &sB[buf][w * 512]);
        gload_lds16(gb + (size_t)64 * K + k0,   &sB[buf][2048 + w * 512]);
    };

    STAGE(0, 0);
    int cur = 0;
    for (int k0 = 0; k0 < K; k0 += 32) {
        if (k0 + 32 < K) {
            STAGE(cur ^ 1, k0 + 32);                         // next tile in flight
            asm volatile("s_waitcnt vmcnt(4)" ::: "memory"); // cur tile landed
        } else {
            asm volatile("s_waitcnt vmcnt(0)" ::: "memory");
        }
        __builtin_amdgcn_s_barrier();                        // cur tile visible

        f16x8 af[4], bf[4];
        #pragma unroll
        for (int mi = 0; mi < 4; ++mi)
            af[mi] = *(const f16x8*)&sA[cur][(wr * 64 + mi * 16 + l15) * 32 + quad * 8];
        #pragma unroll
        for (int ni = 0; ni < 4; ++ni)
            bf[ni] = *(const f16x8*)&sB[cur][(wc * 64 + ni * 16 + l15) * 32 + quad * 8];
        #pragma unroll
        for (int mi = 0; mi < 4; ++mi)
            #pragma unroll
            for (int ni = 0; ni < 4; ++ni)
                acc[mi][ni] = __builtin_amdgcn_mfma_f32_16x16x32_f16(af[mi], bf[ni], acc[mi][ni], 0, 0, 0);

        asm volatile("s_waitcnt lgkmcnt(0)" ::: "memory");   // LDS reads drained
        __builtin_amdgcn_s_barrier();                        // safe to overwrite next iter
        cur ^= 1;
    }

    const int ten = col0 >> 10;                 // tile never straddles tensors
    const float* bias = (ten == 0) ? b0 : (ten == 1) ? b1 : b2;
    OutT* out = (ten == 0) ? o0 : (ten == 1) ? o1 : o2;
    const int nc0 = col0 & (N - 1);

    if constexpr (WITH_FILL) {
        if (ten == 2) {
            // transposed V store: lane holds tokens tok..tok+3 for column colv
            f16* vout = reinterpret_cast<f16*>(o2);
            #pragma unroll
            for (int mi = 0; mi < 4; ++mi)
                #pragma unroll
                for (int ni = 0; ni < 4; ++ni) {
                    const int tok  = row0 + wr * 64 + mi * 16 + quad * 4;
                    const int colv = nc0 + wc * 64 + ni * 16 + l15;
                    const float bvv = bias[colv];
                    f16x4 h4 = {(f16)(acc[mi][ni][0] + bvv), (f16)(acc[mi][ni][1] + bvv),
                                (f16)(acc[mi][ni][2] + bvv), (f16)(acc[mi][ni][3] + bvv)};
                    const int bb = tok >> 11;
                    *(f16x4*)&vout[((size_t)(bb * 1024 + colv)) * 2048 + (tok & 2047)] = h4;
                }
            return;
        }
    }

    #pragma unroll
    for (int mi = 0; mi < 4; ++mi)
        #pragma unroll
        for (int ni = 0; ni < 4; ++ni) {
            const int rbase = row0 + wr * 64 + mi * 16 + quad * 4;
            const int col = nc0 + wc * 64 + ni * 16 + l15;
            const float bv = bias[col];
            #pragma unroll
            for (int r = 0; r < 4; ++r)
                out[(size_t)(rbase + r) * N + col] = (OutT)(acc[mi][ni][r] + bv);
        }
}

// ---------------------------------------------------------------------------
// O-projection GEMM, BM=64 x BN=128, 2-phase double-buffered K-loop.
// ---------------------------------------------------------------------------
__global__ __launch_bounds__(256, 3)
void gemm_o64(const f16* __restrict__ A, const f16* __restrict__ W,
              const float* __restrict__ bias, float* __restrict__ out) {
    constexpr int K = 1024, N = 1024;
    const int t = threadIdx.x;
    const int gid = blockIdx.x;

    __shared__ f16 sA[2][64 * 32];
    __shared__ f16 sB[2][128 * 32];

    const int w = t >> 6, l = t & 63, l15 = l & 15, quad = l >> 4;
    const int col_t = gid & 7, row_t = gid >> 3;
    const int row0 = row_t * 64, col0 = col_t * 128;

    f32x4 acc[4][2];
    #pragma unroll
    for (int i = 0; i < 4; ++i)
        #pragma unroll
        for (int j = 0; j < 2; ++j) acc[i][j] = (f32x4){0.f, 0.f, 0.f, 0.f};

    const int arow = t >> 2;          // 0..63
    const int koff = (t & 3) * 8;
    const f16* ga = A + (size_t)(row0 + arow) * K + koff;
    const f16* gb = W + (size_t)(col0 + arow) * K + koff;

    auto STAGE = [&](int buf, int k0) {
        gload_lds16(ga + k0,                  &sA[buf][w * 512]);
        gload_lds16(gb + k0,                  &sB[buf][w * 512]);
        gload_lds16(gb + (size_t)64 * K + k0, &sB[buf][2048 + w * 512]);
    };

    STAGE(0, 0);
    int cur = 0;
    for (int k0 = 0; k0 < K; k0 += 32) {
        if (k0 + 32 < K) {
            STAGE(cur ^ 1, k0 + 32);
            asm volatile("s_waitcnt vmcnt(3)" ::: "memory");
        } else {
            asm volatile("s_waitcnt vmcnt(0)" ::: "memory");
        }
        __builtin_amdgcn_s_barrier();

        f16x8 af[4], bf[2];
        #pragma unroll
        for (int mi = 0; mi < 4; ++mi)
            af[mi] = *(const f16x8*)&sA[cur][(mi * 16 + l15) * 32 + quad * 8];
        #pragma unroll
        for (int ni = 0; ni < 2; ++ni)
            bf[ni] = *(const f16x8*)&sB[cur][(w * 32 + ni * 16 + l15) * 32 + quad * 8];
        #pragma unroll
        for (int mi = 0; mi < 4; ++mi)
            #pragma unroll
            for (int ni = 0; ni < 2; ++ni)
                acc[mi][ni] = __builtin_amdgcn_mfma_f32_16x16x32_f16(af[mi], bf[ni], acc[mi][ni], 0, 0, 0);

        asm volatile("s_waitcnt lgkmcnt(0)" ::: "memory");
        __builtin_amdgcn_s_barrier();
        cur ^= 1;
    }

    #pragma unroll
    for (int mi = 0; mi < 4; ++mi)
        #pragma unroll
        for (int ni = 0; ni < 2; ++ni) {
            const int rbase = row0 + mi * 16 + quad * 4;
            const int col = col0 + w * 32 + ni * 16 + l15;
            const float bv = bias[col];
            #pragma unroll
            for (int r = 0; r < 4; ++r)
                out[(size_t)(rbase + r) * N + col] = acc[mi][ni][r] + bv;
        }
}

// ---------------------------------------------------------------------------
// Fused band attention + fill, CLUSTERED: blocks [0,1024) = attn (fills CUs
// at 3/CU density), blocks [1024,1792) = fill flowing in behind.
// Q in registers; K/vT staged in LDS; NT band/fill stores.
// ---------------------------------------------------------------------------
__global__ __launch_bounds__(256, 3)
void attn_fused(const f16* __restrict__ qb, const f16* __restrict__ kb,
                const f16* __restrict__ vT, float* __restrict__ attn,
                f16* __restrict__ ctx) {
    const int bid = blockIdx.x;
    const int t = threadIdx.x;

    int aid;
    if (bid < 1024) {
        aid = bid;
    } else {
        fill_rows32(attn, 40960 + (bid - 1024) * 32, t);  // fid [0,768)
        return;
    }

    __shared__ f16 sK[192 * 72];     // overlaid by sP (64*200 <= 192*72) after QK
    __shared__ f16 sVT[64 * 200];    // vT rows: [d][k window], stride 200 (400 B)
    f16* sP = sK;

    const int w = t >> 6, l = t & 63, l15 = l & 15, quad = l >> 4;
    const int tile = aid & 31, h = (aid >> 5) & 15, b = aid >> 9;
    const int q0 = tile * 64;
    const int jbase = q0 - 64;

    // ---- P0a: Q A-fragments straight to registers (rows w*16+l15) ----
    const f16* qg2 = qb + ((size_t)(b * Sc + q0 + w * 16 + l15)) * Dc + h * HDc;
    const f16x8 aq0 = *(const f16x8*)&qg2[quad * 8];
    const f16x8 aq1 = *(const f16x8*)&qg2[32 + quad * 8];

    // ---- P0b: stage K window (192x64), vT window (64x192) ----
    #pragma unroll
    for (int it = 0; it < 6; ++it) {
        const int idx = it * 256 + t;          // 0..1535
        const int r = idx >> 3, c = (idx & 7) * 8;
        int j = jbase + r;
        j = (j < 0) ? 0 : (j > Sc - 1 ? Sc - 1 : j);
        const size_t goff = ((size_t)(b * Sc + j)) * Dc + h * HDc + c;
        *(uint4*)&sK[r * 72 + c] = *(const uint4*)&kb[goff];
    }
    // vT rows: dd = t>>2 (0..63), chunks of 8 f16 along the token window.
    {
        const f16* vrow = vT + ((size_t)((b * Hc + h) * HDc)) * Sc + jbase;
        const int dd = t >> 2;
        #pragma unroll
        for (int it = 0; it < 6; ++it) {
            const int ch = it * 4 + (t & 3);   // 0..23
            *(uint4*)&sVT[dd * 200 + ch * 8] = *(const uint4*)&vrow[(size_t)dd * Sc + ch * 8];
        }
    }
    __syncthreads();

    // ---- QK^T: S[64x192]; wave w owns rows [16w,16w+16) ----
    f32x4 s[12];
    #pragma unroll
    for (int nt = 0; nt < 12; ++nt) s[nt] = (f32x4){0.f, 0.f, 0.f, 0.f};
    #pragma unroll
    for (int nt = 0; nt < 12; ++nt) {
        const f16x8 bk0 = *(const f16x8*)&sK[(nt * 16 + l15) * 72 + quad * 8];
        s[nt] = __builtin_amdgcn_mfma_f32_16x16x32_f16(aq0, bk0, s[nt], 0, 0, 0);
    }
    #pragma unroll
    for (int nt = 0; nt < 12; ++nt) {
        const f16x8 bk1 = *(const f16x8*)&sK[(nt * 16 + l15) * 72 + 32 + quad * 8];
        s[nt] = __builtin_amdgcn_mfma_f32_16x16x32_f16(aq1, bk1, s[nt], 0, 0, 0);
    }

    // ---- in-register softmax; lane holds rows w*16+quad*4+r, cols nt*16+l15
    float invr[4];
    #pragma unroll
    for (int r = 0; r < 4; ++r) {
        const int row = w * 16 + quad * 4 + r;
        const int lo = (row > 64 - q0) ? row : (64 - q0);
        const int hi2 = (row + 128 < 2111 - q0) ? (row + 128) : (2111 - q0);
        float m = -1e30f;
        #pragma unroll
        for (int nt = 0; nt < 12; ++nt) {
            const int jrel = nt * 16 + l15;
            const float v = s[nt][r] * 0.125f;
            if (jrel >= lo && jrel <= hi2) m = fmaxf(m, v);
        }
        #pragma unroll
        for (int k = 1; k < 16; k <<= 1) m = fmaxf(m, __shfl_xor(m, k, 64));
        float sum = 0.f;
        #pragma unroll
        for (int nt = 0; nt < 12; ++nt) {
            const int jrel = nt * 16 + l15;
            const float v = s[nt][r] * 0.125f;
            const float e = (jrel >= lo && jrel <= hi2) ? __expf(v - m) : 0.f;
            s[nt][r] = e;
            sum += e;
        }
        #pragma unroll
        for (int k = 1; k < 16; k <<= 1) sum += __shfl_xor(sum, k, 64);
        invr[r] = 1.f / sum;
    }
    __syncthreads();   // sK reads done -> safe to overlay sP

    // ---- P2: write P to LDS + aligned global window [a0,a1), NT stores ----
    float* abase = attn + ((size_t)(b * Hc + h) * Sc) * Sc;
    #pragma unroll
    for (int r = 0; r < 4; ++r) {
        const int row = w * 16 + quad * 4 + r;
        const int i = q0 + row;
        const int lo0 = (i > 64) ? (i - 64) : 0;
        const int a0 = lo0 & ~31;
        const int hi0 = (i < Sc - 65) ? (i + 64) : (Sc - 1);
        int a1 = (hi0 + 32) & ~31; if (a1 > Sc) a1 = Sc;
        const int alo = a0 - jbase, ahi = a1 - jbase;
        #pragma unroll
        for (int nt = 0; nt < 12; ++nt) {
            const int jrel = nt * 16 + l15;
            const float p = s[nt][r] * invr[r];
            sP[row * 200 + jrel] = (f16)p;
            if (jrel >= alo && jrel < ahi)
                __builtin_nontemporal_store(p, &abase[(size_t)i * Sc + (jbase + jrel)]);
        }
    }
    __syncthreads();

    // ---- P3: ctx[64x64] = P[64x192] @ V[192x64], V from sVT via b128 ----
    f32x4 o[4];
    #pragma unroll
    for (int dt = 0; dt < 4; ++dt) o[dt] = (f32x4){0.f, 0.f, 0.f, 0.f};
    #pragma unroll
    for (int ks = 0; ks < 6; ++ks) {
        const f16x8 ap = *(const f16x8*)&sP[(w * 16 + l15) * 200 + ks * 32 + quad * 8];
        #pragma unroll
        for (int dt = 0; dt < 4; ++dt) {
            const f16x8 bv = *(const f16x8*)&sVT[(dt * 16 + l15) * 200 + ks * 32 + quad * 8];
            o[dt] = __builtin_amdgcn_mfma_f32_16x16x32_f16(ap, bv, o[dt], 0, 0, 0);
        }
    }
    f16* cg = ctx + ((size_t)(b * Sc + q0)) * Dc + h * HDc;
    #pragma unroll
    for (int dt = 0; dt < 4; ++dt)
        #pragma unroll
        for (int r = 0; r < 4; ++r) {
            const int row = w * 16 + quad * 4 + r;
            cg[(size_t)row * Dc + dt * 16 + l15] = (f16)o[dt][r];
        }
}

// ---------------------------------------------------------------------------
extern "C" void kernel_launch(void* const* d_in, const int* in_sizes, int n_in,
                              void* d_out, int out_size, void* d_ws, size_t ws_size,
                              hipStream_t stream) {
    const float* x  = (const float*)d_in[0];
    const float* Wq = (const float*)d_in[1];
    const float* bq = (const float*)d_in[2];
    const float* Wk = (const float*)d_in[3];
    const float* bk = (const float*)d_in[4];
    const float* Wv = (const float*)d_in[5];
    const float* bv = (const float*)d_in[6];
    const float* Wo = (const float*)d_in[7];
    const float* bo = (const float*)d_in[8];

    float* out  = (float*)d_out;
    float* attn = out + PROJ;

    char* ws = (char*)d_ws;
    f16* Wcat  = (f16*)ws;                 // [4][1024][1024] fp16 = 8 MB
    f16* x_f16 = (f16*)(ws + (size_t)8  * 1024 * 1024);
    f16* q_f16 = (f16*)(ws + (size_t)16 * 1024 * 1024);
    f16* k_f16 = (f16*)(ws + (size_t)24 * 1024 * 1024);
    f16* c_f16 = (f16*)(ws + (size_t)40 * 1024 * 1024);
    // transposed V [2048 d-rows][2048 tokens] fp16 with 512 B guards each side
    f16* vT    = (f16*)(ws + (size_t)48 * 1024 * 1024 + 512);

    pack_all<<<dim3(8193), dim3(256), 0, stream>>>(x, Wq, Wk, Wv, Wo, x_f16, Wcat, vT);

    // QKV GEMM [0,768) clustered first (256 CUs x 3) + fill [768,2048)
    gemm_mega<f16, true><<<dim3(2048), dim3(256), 0, stream>>>(
        x_f16, Wcat, bq, bk, bv, q_f16, k_f16, vT, attn, 24);

    // attention [0,1024) clustered first + fill [1024,1792)
    attn_fused<<<dim3(1792), dim3(256), 0, stream>>>(
        q_f16, k_f16, vT, attn, c_f16);

    // O projection: BM=64 tiles, 512 blocks, pipelined
    gemm_o64<<<dim3(512), dim3(256), 0, stream>>>(
        c_f16, Wcat + 3 * WN, bo, out);
}

// Round 14
// 618.453 us; speedup vs baseline: 1.2266x; 1.0141x over previous
//
#include <hip/hip_runtime.h>
#include <math.h>
#include <stdint.h>

typedef _Float16 f16;
typedef f16   f16x8 __attribute__((ext_vector_type(8)));
typedef f16   f16x4 __attribute__((ext_vector_type(4)));
typedef float f32x4 __attribute__((ext_vector_type(4)));
typedef unsigned int u32x4 __attribute__((ext_vector_type(4)));   // native vector for NT stores

// async 16B global->LDS (wave-uniform LDS base + lane*16 layout required)
__device__ __forceinline__ void gload_lds16(const void* g, void* l) {
    unsigned int off = (unsigned int)(uintptr_t)l;
    auto lp = (__attribute__((address_space(3))) unsigned int*)(uintptr_t)off;
    auto gp = (const __attribute__((address_space(1))) unsigned int*)(uintptr_t)g;
    __builtin_amdgcn_global_load_lds(gp, lp, 16, 0, 0);
}

constexpr int Bc = 2, Sc = 2048, Dc = 1024, Hc = 16, HDc = 64;
constexpr size_t PROJ = (size_t)Bc * Sc * Dc;     // 4,194,304
constexpr size_t WN   = (size_t)Dc * Dc;          // 1,048,576

// ---------------------------------------------------------------------------
// Band-complement zero fill: 32 rows/block; NT stores (never re-read).
// ---------------------------------------------------------------------------
__device__ __forceinline__ void fill_rows32(float* __restrict__ attn, int grow0, int t) {
    const u32x4 z = {0u, 0u, 0u, 0u};
    for (int rr = 0; rr < 32; ++rr) {
        const int gr = grow0 + rr;
        const int i = gr & (Sc - 1);
        const int lo = (i > 64) ? (i - 64) : 0;
        const int a0 = lo & ~31;
        const int hi = (i < Sc - 65) ? (i + 64) : (Sc - 1);
        int a1 = (hi + 32) & ~31; if (a1 > Sc) a1 = Sc;
        u32x4* rowp = (u32x4*)(attn + (size_t)gr * Sc);
        const int n4L = a0 >> 2;
        const int r0  = a1 >> 2;
        const int tot = n4L + (512 - r0);
        for (int idx = t; idx < tot; idx += 256) {
            const int p = (idx < n4L) ? idx : (r0 + idx - n4L);
            __builtin_nontemporal_store(z, &rowp[p]);
        }
    }
}

// ---------------------------------------------------------------------------
// fp32 -> fp16 pack: x (4096 blocks) + 4 weight tensors (4x1024 blocks)
// + 1 guard block zeroing the 512B margins around vT.
// ---------------------------------------------------------------------------
__global__ __launch_bounds__(256)
void pack_all(const float* __restrict__ x,
              const float* __restrict__ w0, const float* __restrict__ w1,
              const float* __restrict__ w2, const float* __restrict__ w3,
              f16* __restrict__ xd, f16* __restrict__ wd, f16* __restrict__ vT) {
    const int bid = blockIdx.x;
    if (bid == 8192) {
        const uint4 z = {0u, 0u, 0u, 0u};
        uint4* pre  = (uint4*)(vT - 256);                      // 512 B
        uint4* post = (uint4*)(vT + (size_t)4 * 1024 * 1024);  // 512 B
        const int t = threadIdx.x;
        if (t < 32) pre[t] = z;
        else if (t < 64) post[t - 32] = z;
        return;
    }
    const float* src;
    f16* dst;
    int off4;
    if (bid < 4096) {
        src = x; dst = xd; off4 = bid;
    } else {
        const int wi = (bid - 4096) >> 10;
        const int r  = (bid - 4096) & 1023;
        src = (wi == 0) ? w0 : (wi == 1) ? w1 : (wi == 2) ? w2 : w3;
        dst = wd + (size_t)wi * WN;
        off4 = r;
    }
    const int i = off4 * 256 + threadIdx.x;
    float4 f = ((const float4*)src)[i];
    f16x4 h = {(f16)f.x, (f16)f.y, (f16)f.z, (f16)f.w};
    ((f16x4*)dst)[i] = h;
}

// ---------------------------------------------------------------------------
// QKV GEMM + fill, STAGGERED residency mix: the first 768 block IDs (the
// initial resident set at 3 blocks/CU) are (G,G,F) triplets -> each CU holds
// ~2 GEMM + 1 fill: GEMM near full density AND write pipe busy from t=0.
// Remaining 1280 IDs are (G,F,F,F,F) -> fill-dominant tail with GEMM trickle.
// (Clustered was serial phases; uniform 3:5 starved GEMM -- R7/R13 evidence.)
// 2-phase double-buffered K-loop; V (ten==2) stored TRANSPOSED.
// ---------------------------------------------------------------------------
template <typename OutT, bool WITH_FILL>
__global__ __launch_bounds__(256, 3)
void gemm_mega(const f16* __restrict__ A, const f16* __restrict__ W,
               const float* __restrict__ b0, const float* __restrict__ b1,
               const float* __restrict__ b2,
               OutT* __restrict__ o0, OutT* __restrict__ o1, OutT* __restrict__ o2,
               float* __restrict__ fill, int n_ct) {
    constexpr int K = 1024, N = 1024;
    const int bid = blockIdx.x;
    const int t = threadIdx.x;

    int gid = bid;
    if (WITH_FILL) {
        int fid = -1;
        if (bid < 768) {
            const int g3 = bid / 3, l3 = bid - g3 * 3;
            if (l3 < 2) gid = g3 * 2 + l3;          // [0,512)
            else        fid = g3;                    // [0,256)
        } else {
            const int idx = bid - 768;
            const int g5 = idx / 5, l5 = idx - g5 * 5;
            if (l5 == 0) gid = 512 + g5;             // [512,768)
            else         fid = 256 + g5 * 4 + (l5 - 1);  // [256,1280)
        }
        if (fid >= 0) {
            fill_rows32(fill, fid * 32, t);
            return;
        }
    }

    __shared__ f16 sA[2][128 * 32];
    __shared__ f16 sB[2][128 * 32];

    const int w = t >> 6, l = t & 63, l15 = l & 15, quad = l >> 4;
    const int col_t = gid % n_ct, row_t = gid / n_ct;
    const int row0 = row_t * 128, col0 = col_t * 128;
    const int wr = w >> 1, wc = w & 1;

    f32x4 acc[4][4];
    #pragma unroll
    for (int i = 0; i < 4; ++i)
        #pragma unroll
        for (int j = 0; j < 4; ++j) acc[i][j] = (f32x4){0.f, 0.f, 0.f, 0.f};

    const int arow = t >> 2;          // 0..63
    const int koff = (t & 3) * 8;     // 8 f16 = 16B
    const f16* ga = A + (size_t)(row0 + arow) * K + koff;
    const f16* gb = W + (size_t)(col0 + arow) * K + koff;

    auto STAGE = [&](int buf, int k0) {
        gload_lds16(ga + k0,                    &sA[buf][w * 512]);
        gload_lds16(ga + (size_t)64 * K + k0,   &sA[buf][2048 + w * 512]);
        gload_lds16(gb + k0,                    &sB[buf][w * 512]);
        gload_lds16(gb + (size_t)64 * K + k0,   &sB[buf][2048 + w * 512]);
    };

    STAGE(0, 0);
    int cur = 0;
    for (int k0 = 0; k0 < K; k0 += 32) {
        if (k0 + 32 < K) {
            STAGE(cur ^ 1, k0 + 32);                         // next tile in flight
            asm volatile("s_waitcnt vmcnt(4)" ::: "memory"); // cur tile landed
        } else {
            asm volatile("s_waitcnt vmcnt(0)" ::: "memory");
        }
        __builtin_amdgcn_s_barrier();                        // cur tile visible

        f16x8 af[4], bf[4];
        #pragma unroll
        for (int mi = 0; mi < 4; ++mi)
            af[mi] = *(const f16x8*)&sA[cur][(wr * 64 + mi * 16 + l15) * 32 + quad * 8];
        #pragma unroll
        for (int ni = 0; ni < 4; ++ni)
            bf[ni] = *(const f16x8*)&sB[cur][(wc * 64 + ni * 16 + l15) * 32 + quad * 8];
        #pragma unroll
        for (int mi = 0; mi < 4; ++mi)
            #pragma unroll
            for (int ni = 0; ni < 4; ++ni)
                acc[mi][ni] = __builtin_amdgcn_mfma_f32_16x16x32_f16(af[mi], bf[ni], acc[mi][ni], 0, 0, 0);

        asm volatile("s_waitcnt lgkmcnt(0)" ::: "memory");   // LDS reads drained
        __builtin_amdgcn_s_barrier();                        // safe to overwrite next iter
        cur ^= 1;
    }

    const int ten = col0 >> 10;                 // tile never straddles tensors
    const float* bias = (ten == 0) ? b0 : (ten == 1) ? b1 : b2;
    OutT* out = (ten == 0) ? o0 : (ten == 1) ? o1 : o2;
    const int nc0 = col0 & (N - 1);

    if constexpr (WITH_FILL) {
        if (ten == 2) {
            // transposed V store: lane holds tokens tok..tok+3 for column colv
            f16* vout = reinterpret_cast<f16*>(o2);
            #pragma unroll
            for (int mi = 0; mi < 4; ++mi)
                #pragma unroll
                for (int ni = 0; ni < 4; ++ni) {
                    const int tok  = row0 + wr * 64 + mi * 16 + quad * 4;
                    const int colv = nc0 + wc * 64 + ni * 16 + l15;
                    const float bvv = bias[colv];
                    f16x4 h4 = {(f16)(acc[mi][ni][0] + bvv), (f16)(acc[mi][ni][1] + bvv),
                                (f16)(acc[mi][ni][2] + bvv), (f16)(acc[mi][ni][3] + bvv)};
                    const int bb = tok >> 11;
                    *(f16x4*)&vout[((size_t)(bb * 1024 + colv)) * 2048 + (tok & 2047)] = h4;
                }
            return;
        }
    }

    #pragma unroll
    for (int mi = 0; mi < 4; ++mi)
        #pragma unroll
        for (int ni = 0; ni < 4; ++ni) {
            const int rbase = row0 + wr * 64 + mi * 16 + quad * 4;
            const int col = nc0 + wc * 64 + ni * 16 + l15;
            const float bv = bias[col];
            #pragma unroll
            for (int r = 0; r < 4; ++r)
                out[(size_t)(rbase + r) * N + col] = (OutT)(acc[mi][ni][r] + bv);
        }
}

// ---------------------------------------------------------------------------
// O-projection GEMM, BM=64 x BN=128, 2-phase double-buffered K-loop.
// ---------------------------------------------------------------------------
__global__ __launch_bounds__(256, 3)
void gemm_o64(const f16* __restrict__ A, const f16* __restrict__ W,
              const float* __restrict__ bias, float* __restrict__ out) {
    constexpr int K = 1024, N = 1024;
    const int t = threadIdx.x;
    const int gid = blockIdx.x;

    __shared__ f16 sA[2][64 * 32];
    __shared__ f16 sB[2][128 * 32];

    const int w = t >> 6, l = t & 63, l15 = l & 15, quad = l >> 4;
    const int col_t = gid & 7, row_t = gid >> 3;
    const int row0 = row_t * 64, col0 = col_t * 128;

    f32x4 acc[4][2];
    #pragma unroll
    for (int i = 0; i < 4; ++i)
        #pragma unroll
        for (int j = 0; j < 2; ++j) acc[i][j] = (f32x4){0.f, 0.f, 0.f, 0.f};

    const int arow = t >> 2;          // 0..63
    const int koff = (t & 3) * 8;
    const f16* ga = A + (size_t)(row0 + arow) * K + koff;
    const f16* gb = W + (size_t)(col0 + arow) * K + koff;

    auto STAGE = [&](int buf, int k0) {
        gload_lds16(ga + k0,                  &sA[buf][w * 512]);
        gload_lds16(gb + k0,                  &sB[buf][w * 512]);
        gload_lds16(gb + (size_t)64 * K + k0, &sB[buf][2048 + w * 512]);
    };

    STAGE(0, 0);
    int cur = 0;
    for (int k0 = 0; k0 < K; k0 += 32) {
        if (k0 + 32 < K) {
            STAGE(cur ^ 1, k0 + 32);
            asm volatile("s_waitcnt vmcnt(3)" ::: "memory");
        } else {
            asm volatile("s_waitcnt vmcnt(0)" ::: "memory");
        }
        __builtin_amdgcn_s_barrier();

        f16x8 af[4], bf[2];
        #pragma unroll
        for (int mi = 0; mi < 4; ++mi)
            af[mi] = *(const f16x8*)&sA[cur][(mi * 16 + l15) * 32 + quad * 8];
        #pragma unroll
        for (int ni = 0; ni < 2; ++ni)
            bf[ni] = *(const f16x8*)&sB[cur][(w * 32 + ni * 16 + l15) * 32 + quad * 8];
        #pragma unroll
        for (int mi = 0; mi < 4; ++mi)
            #pragma unroll
            for (int ni = 0; ni < 2; ++ni)
                acc[mi][ni] = __builtin_amdgcn_mfma_f32_16x16x32_f16(af[mi], bf[ni], acc[mi][ni], 0, 0, 0);

        asm volatile("s_waitcnt lgkmcnt(0)" ::: "memory");
        __builtin_amdgcn_s_barrier();
        cur ^= 1;
    }

    #pragma unroll
    for (int mi = 0; mi < 4; ++mi)
        #pragma unroll
        for (int ni = 0; ni < 2; ++ni) {
            const int rbase = row0 + mi * 16 + quad * 4;
            const int col = col0 + w * 32 + ni * 16 + l15;
            const float bv = bias[col];
            #pragma unroll
            for (int r = 0; r < 4; ++r)
                out[(size_t)(rbase + r) * N + col] = acc[mi][ni][r] + bv;
        }
}

// ---------------------------------------------------------------------------
// Fused band attention + fill, STAGGERED: first 768 IDs = (A,A,F) triplets
// (512 attn + 256 fill -> ~2 attn + 1 fill per CU initially); remaining
// 1024 IDs alternate (A,F) (512 + 512).
// Q in registers; K/vT staged in LDS; NT band/fill stores.
// ---------------------------------------------------------------------------
__global__ __launch_bounds__(256, 3)
void attn_fused(const f16* __restrict__ qb, const f16* __restrict__ kb,
                const f16* __restrict__ vT, float* __restrict__ attn,
                f16* __restrict__ ctx) {
    const int bid = blockIdx.x;
    const int t = threadIdx.x;

    int aid, fid = -1;
    if (bid < 768) {
        const int g3 = bid / 3, l3 = bid - g3 * 3;
        if (l3 < 2) aid = g3 * 2 + l3;              // [0,512)
        else        fid = g3;                        // [0,256)
    } else {
        const int idx = bid - 768;
        if ((idx & 1) == 0) aid = 512 + (idx >> 1);  // [512,1024)
        else                fid = 256 + (idx >> 1);  // [256,768)
    }
    if (fid >= 0) {
        fill_rows32(attn, 40960 + fid * 32, t);
        return;
    }

    __shared__ f16 sK[192 * 72];     // overlaid by sP (64*200 <= 192*72) after QK
    __shared__ f16 sVT[64 * 200];    // vT rows: [d][k window], stride 200 (400 B)
    f16* sP = sK;

    const int w = t >> 6, l = t & 63, l15 = l & 15, quad = l >> 4;
    const int tile = aid & 31, h = (aid >> 5) & 15, b = aid >> 9;
    const int q0 = tile * 64;
    const int jbase = q0 - 64;

    // ---- P0a: Q A-fragments straight to registers (rows w*16+l15) ----
    const f16* qg2 = qb + ((size_t)(b * Sc + q0 + w * 16 + l15)) * Dc + h * HDc;
    const f16x8 aq0 = *(const f16x8*)&qg2[quad * 8];
    const f16x8 aq1 = *(const f16x8*)&qg2[32 + quad * 8];

    // ---- P0b: stage K window (192x64), vT window (64x192) ----
    #pragma unroll
    for (int it = 0; it < 6; ++it) {
        const int idx = it * 256 + t;          // 0..1535
        const int r = idx >> 3, c = (idx & 7) * 8;
        int j = jbase + r;
        j = (j < 0) ? 0 : (j > Sc - 1 ? Sc - 1 : j);
        const size_t goff = ((size_t)(b * Sc + j)) * Dc + h * HDc + c;
        *(uint4*)&sK[r * 72 + c] = *(const uint4*)&kb[goff];
    }
    // vT rows: dd = t>>2 (0..63), chunks of 8 f16 along the token window.
    {
        const f16* vrow = vT + ((size_t)((b * Hc + h) * HDc)) * Sc + jbase;
        const int dd = t >> 2;
        #pragma unroll
        for (int it = 0; it < 6; ++it) {
            const int ch = it * 4 + (t & 3);   // 0..23
            *(uint4*)&sVT[dd * 200 + ch * 8] = *(const uint4*)&vrow[(size_t)dd * Sc + ch * 8];
        }
    }
    __syncthreads();

    // ---- QK^T: S[64x192]; wave w owns rows [16w,16w+16) ----
    f32x4 s[12];
    #pragma unroll
    for (int nt = 0; nt < 12; ++nt) s[nt] = (f32x4){0.f, 0.f, 0.f, 0.f};
    #pragma unroll
    for (int nt = 0; nt < 12; ++nt) {
        const f16x8 bk0 = *(const f16x8*)&sK[(nt * 16 + l15) * 72 + quad * 8];
        s[nt] = __builtin_amdgcn_mfma_f32_16x16x32_f16(aq0, bk0, s[nt], 0, 0, 0);
    }
    #pragma unroll
    for (int nt = 0; nt < 12; ++nt) {
        const f16x8 bk1 = *(const f16x8*)&sK[(nt * 16 + l15) * 72 + 32 + quad * 8];
        s[nt] = __builtin_amdgcn_mfma_f32_16x16x32_f16(aq1, bk1, s[nt], 0, 0, 0);
    }

    // ---- in-register softmax; lane holds rows w*16+quad*4+r, cols nt*16+l15
    float invr[4];
    #pragma unroll
    for (int r = 0; r < 4; ++r) {
        const int row = w * 16 + quad * 4 + r;
        const int lo = (row > 64 - q0) ? row : (64 - q0);
        const int hi2 = (row + 128 < 2111 - q0) ? (row + 128) : (2111 - q0);
        float m = -1e30f;
        #pragma unroll
        for (int nt = 0; nt < 12; ++nt) {
            const int jrel = nt * 16 + l15;
            const float v = s[nt][r] * 0.125f;
            if (jrel >= lo && jrel <= hi2) m = fmaxf(m, v);
        }
        #pragma unroll
        for (int k = 1; k < 16; k <<= 1) m = fmaxf(m, __shfl_xor(m, k, 64));
        float sum = 0.f;
        #pragma unroll
        for (int nt = 0; nt < 12; ++nt) {
            const int jrel = nt * 16 + l15;
            const float v = s[nt][r] * 0.125f;
            const float e = (jrel >= lo && jrel <= hi2) ? __expf(v - m) : 0.f;
            s[nt][r] = e;
            sum += e;
        }
        #pragma unroll
        for (int k = 1; k < 16; k <<= 1) sum += __shfl_xor(sum, k, 64);
        invr[r] = 1.f / sum;
    }
    __syncthreads();   // sK reads done -> safe to overlay sP

    // ---- P2: write P to LDS + aligned global window [a0,a1), NT stores ----
    float* abase = attn + ((size_t)(b * Hc + h) * Sc) * Sc;
    #pragma unroll
    for (int r = 0; r < 4; ++r) {
        const int row = w * 16 + quad * 4 + r;
        const int i = q0 + row;
        const int lo0 = (i > 64) ? (i - 64) : 0;
        const int a0 = lo0 & ~31;
        const int hi0 = (i < Sc - 65) ? (i + 64) : (Sc - 1);
        int a1 = (hi0 + 32) & ~31; if (a1 > Sc) a1 = Sc;
        const int alo = a0 - jbase, ahi = a1 - jbase;
        #pragma unroll
        for (int nt = 0; nt < 12; ++nt) {
            const int jrel = nt * 16 + l15;
            const float p = s[nt][r] * invr[r];
            sP[row * 200 + jrel] = (f16)p;
            if (jrel >= alo && jrel < ahi)
                __builtin_nontemporal_store(p, &abase[(size_t)i * Sc + (jbase + jrel)]);
        }
    }
    __syncthreads();

    // ---- P3: ctx[64x64] = P[64x192] @ V[192x64], V from sVT via b128 ----
    f32x4 o[4];
    #pragma unroll
    for (int dt = 0; dt < 4; ++dt) o[dt] = (f32x4){0.f, 0.f, 0.f, 0.f};
    #pragma unroll
    for (int ks = 0; ks < 6; ++ks) {
        const f16x8 ap = *(const f16x8*)&sP[(w * 16 + l15) * 200 + ks * 32 + quad * 8];
        #pragma unroll
        for (int dt = 0; dt < 4; ++dt) {
            const f16x8 bv = *(const f16x8*)&sVT[(dt * 16 + l15) * 200 + ks * 32 + quad * 8];
            o[dt] = __builtin_amdgcn_mfma_f32_16x16x32_f16(ap, bv, o[dt], 0, 0, 0);
        }
    }
    f16* cg = ctx + ((size_t)(b * Sc + q0)) * Dc + h * HDc;
    #pragma unroll
    for (int dt = 0; dt < 4; ++dt)
        #pragma unroll
        for (int r = 0; r < 4; ++r) {
            const int row = w * 16 + quad * 4 + r;
            cg[(size_t)row * Dc + dt * 16 + l15] = (f16)o[dt][r];
        }
}

// ---------------------------------------------------------------------------
extern "C" void kernel_launch(void* const* d_in, const int* in_sizes, int n_in,
                              void* d_out, int out_size, void* d_ws, size_t ws_size,
                              hipStream_t stream) {
    const float* x  = (const float*)d_in[0];
    const float* Wq = (const float*)d_in[1];
    const float* bq = (const float*)d_in[2];
    const float* Wk = (const float*)d_in[3];
    const float* bk = (const float*)d_in[4];
    const float* Wv = (const float*)d_in[5];
    const float* bv = (const float*)d_in[6];
    const float* Wo = (const float*)d_in[7];
    const float* bo = (const float*)d_in[8];

    float* out  = (float*)d_out;
    float* attn = out + PROJ;

    char* ws = (char*)d_ws;
    f16* Wcat  = (f16*)ws;                 // [4][1024][1024] fp16 = 8 MB
    f16* x_f16 = (f16*)(ws + (size_t)8  * 1024 * 1024);
    f16* q_f16 = (f16*)(ws + (size_t)16 * 1024 * 1024);
    f16* k_f16 = (f16*)(ws + (size_t)24 * 1024 * 1024);
    f16* c_f16 = (f16*)(ws + (size_t)40 * 1024 * 1024);
    // transposed V [2048 d-rows][2048 tokens] fp16 with 512 B guards each side
    f16* vT    = (f16*)(ws + (size_t)48 * 1024 * 1024 + 512);

    pack_all<<<dim3(8193), dim3(256), 0, stream>>>(x, Wq, Wk, Wv, Wo, x_f16, Wcat, vT);

    // QKV GEMM + fill, staggered 2:1 head / 1:4 tail
    gemm_mega<f16, true><<<dim3(2048), dim3(256), 0, stream>>>(
        x_f16, Wcat, bq, bk, bv, q_f16, k_f16, vT, attn, 24);

    // attention + fill, staggered 2:1 head / 1:1 tail
    attn_fused<<<dim3(1792), dim3(256), 0, stream>>>(
        q_f16, k_f16, vT, attn, c_f16);

    // O projection: BM=64 tiles, 512 blocks, pipelined
    gemm_o64<<<dim3(512), dim3(256), 0, stream>>>(
        c_f16, Wcat + 3 * WN, bo, out);
}

// Round 15
// 616.970 us; speedup vs baseline: 1.2296x; 1.0024x over previous
//
#include <hip/hip_runtime.h>
#include <math.h>
#include <stdint.h>

typedef _Float16 f16;
typedef f16   f16x8 __attribute__((ext_vector_type(8)));
typedef f16   f16x4 __attribute__((ext_vector_type(4)));
typedef float f32x4 __attribute__((ext_vector_type(4)));
typedef unsigned int u32x4 __attribute__((ext_vector_type(4)));   // native vector for NT stores

// async 16B global->LDS (wave-uniform LDS base + lane*16 layout required)
__device__ __forceinline__ void gload_lds16(const void* g, void* l) {
    unsigned int off = (unsigned int)(uintptr_t)l;
    auto lp = (__attribute__((address_space(3))) unsigned int*)(uintptr_t)off;
    auto gp = (const __attribute__((address_space(1))) unsigned int*)(uintptr_t)g;
    __builtin_amdgcn_global_load_lds(gp, lp, 16, 0, 0);
}

constexpr int Bc = 2, Sc = 2048, Dc = 1024, Hc = 16, HDc = 64;
constexpr size_t PROJ = (size_t)Bc * Sc * Dc;     // 4,194,304
constexpr size_t WN   = (size_t)Dc * Dc;          // 1,048,576

// ---------------------------------------------------------------------------
// Band-complement zero fill: 32 rows/block; NT stores (never re-read).
// ---------------------------------------------------------------------------
__device__ __forceinline__ void fill_rows32(float* __restrict__ attn, int grow0, int t) {
    const u32x4 z = {0u, 0u, 0u, 0u};
    for (int rr = 0; rr < 32; ++rr) {
        const int gr = grow0 + rr;
        const int i = gr & (Sc - 1);
        const int lo = (i > 64) ? (i - 64) : 0;
        const int a0 = lo & ~31;
        const int hi = (i < Sc - 65) ? (i + 64) : (Sc - 1);
        int a1 = (hi + 32) & ~31; if (a1 > Sc) a1 = Sc;
        u32x4* rowp = (u32x4*)(attn + (size_t)gr * Sc);
        const int n4L = a0 >> 2;
        const int r0  = a1 >> 2;
        const int tot = n4L + (512 - r0);
        for (int idx = t; idx < tot; idx += 256) {
            const int p = (idx < n4L) ? idx : (r0 + idx - n4L);
            __builtin_nontemporal_store(z, &rowp[p]);
        }
    }
}

// ---------------------------------------------------------------------------
// fp32 -> fp16 pack: x (4096 blocks) + 4 weight tensors (4x1024 blocks)
// + 1 guard block zeroing the 512B margins around vT.
// ---------------------------------------------------------------------------
__global__ __launch_bounds__(256)
void pack_all(const float* __restrict__ x,
              const float* __restrict__ w0, const float* __restrict__ w1,
              const float* __restrict__ w2, const float* __restrict__ w3,
              f16* __restrict__ xd, f16* __restrict__ wd, f16* __restrict__ vT) {
    const int bid = blockIdx.x;
    if (bid == 8192) {
        const uint4 z = {0u, 0u, 0u, 0u};
        uint4* pre  = (uint4*)(vT - 256);                      // 512 B
        uint4* post = (uint4*)(vT + (size_t)4 * 1024 * 1024);  // 512 B
        const int t = threadIdx.x;
        if (t < 32) pre[t] = z;
        else if (t < 64) post[t - 32] = z;
        return;
    }
    const float* src;
    f16* dst;
    int off4;
    if (bid < 4096) {
        src = x; dst = xd; off4 = bid;
    } else {
        const int wi = (bid - 4096) >> 10;
        const int r  = (bid - 4096) & 1023;
        src = (wi == 0) ? w0 : (wi == 1) ? w1 : (wi == 2) ? w2 : w3;
        dst = wd + (size_t)wi * WN;
        off4 = r;
    }
    const int i = off4 * 256 + threadIdx.x;
    float4 f = ((const float4*)src)[i];
    f16x4 h = {(f16)f.x, (f16)f.y, (f16)f.z, (f16)f.w};
    ((f16x4*)dst)[i] = h;
}

// ---------------------------------------------------------------------------
// QKV GEMM + fill, STAGGERED residency mix (R14-verified mechanism), fill
// share rebalanced down to 1024 blocks (rows [0,32768)): head 768 IDs =
// (G,G,F) triplets (512G+256F -> ~2 compute + 1 fill per CU from t=0);
// tail 1024 IDs = (G,F,F,F) (256G+768F).
// 2-phase double-buffered K-loop; V (ten==2) stored TRANSPOSED.
// ---------------------------------------------------------------------------
template <typename OutT, bool WITH_FILL>
__global__ __launch_bounds__(256, 3)
void gemm_mega(const f16* __restrict__ A, const f16* __restrict__ W,
               const float* __restrict__ b0, const float* __restrict__ b1,
               const float* __restrict__ b2,
               OutT* __restrict__ o0, OutT* __restrict__ o1, OutT* __restrict__ o2,
               float* __restrict__ fill, int n_ct) {
    constexpr int K = 1024, N = 1024;
    const int bid = blockIdx.x;
    const int t = threadIdx.x;

    int gid = bid;
    if (WITH_FILL) {
        int fid = -1;
        if (bid < 768) {
            const int g3 = bid / 3, l3 = bid - g3 * 3;
            if (l3 < 2) gid = g3 * 2 + l3;          // [0,512)
            else        fid = g3;                    // [0,256)
        } else {
            const int idx = bid - 768;               // [0,1024)
            const int g4 = idx >> 2, l4 = idx & 3;
            if (l4 == 0) gid = 512 + g4;             // [512,768)
            else         fid = 256 + g4 * 3 + (l4 - 1);  // [256,1024)
        }
        if (fid >= 0) {
            fill_rows32(fill, fid * 32, t);          // rows [0,32768)
            return;
        }
    }

    __shared__ f16 sA[2][128 * 32];
    __shared__ f16 sB[2][128 * 32];

    const int w = t >> 6, l = t & 63, l15 = l & 15, quad = l >> 4;
    const int col_t = gid % n_ct, row_t = gid / n_ct;
    const int row0 = row_t * 128, col0 = col_t * 128;
    const int wr = w >> 1, wc = w & 1;

    f32x4 acc[4][4];
    #pragma unroll
    for (int i = 0; i < 4; ++i)
        #pragma unroll
        for (int j = 0; j < 4; ++j) acc[i][j] = (f32x4){0.f, 0.f, 0.f, 0.f};

    const int arow = t >> 2;          // 0..63
    const int koff = (t & 3) * 8;     // 8 f16 = 16B
    const f16* ga = A + (size_t)(row0 + arow) * K + koff;
    const f16* gb = W + (size_t)(col0 + arow) * K + koff;

    auto STAGE = [&](int buf, int k0) {
        gload_lds16(ga + k0,                    &sA[buf][w * 512]);
        gload_lds16(ga + (size_t)64 * K + k0,   &sA[buf][2048 + w * 512]);
        gload_lds16(gb + k0,                    &sB[buf][w * 512]);
        gload_lds16(gb + (size_t)64 * K + k0,   &sB[buf][2048 + w * 512]);
    };

    STAGE(0, 0);
    int cur = 0;
    for (int k0 = 0; k0 < K; k0 += 32) {
        if (k0 + 32 < K) {
            STAGE(cur ^ 1, k0 + 32);                         // next tile in flight
            asm volatile("s_waitcnt vmcnt(4)" ::: "memory"); // cur tile landed
        } else {
            asm volatile("s_waitcnt vmcnt(0)" ::: "memory");
        }
        __builtin_amdgcn_s_barrier();                        // cur tile visible

        f16x8 af[4], bf[4];
        #pragma unroll
        for (int mi = 0; mi < 4; ++mi)
            af[mi] = *(const f16x8*)&sA[cur][(wr * 64 + mi * 16 + l15) * 32 + quad * 8];
        #pragma unroll
        for (int ni = 0; ni < 4; ++ni)
            bf[ni] = *(const f16x8*)&sB[cur][(wc * 64 + ni * 16 + l15) * 32 + quad * 8];
        #pragma unroll
        for (int mi = 0; mi < 4; ++mi)
            #pragma unroll
            for (int ni = 0; ni < 4; ++ni)
                acc[mi][ni] = __builtin_amdgcn_mfma_f32_16x16x32_f16(af[mi], bf[ni], acc[mi][ni], 0, 0, 0);

        asm volatile("s_waitcnt lgkmcnt(0)" ::: "memory");   // LDS reads drained
        __builtin_amdgcn_s_barrier();                        // safe to overwrite next iter
        cur ^= 1;
    }

    const int ten = col0 >> 10;                 // tile never straddles tensors
    const float* bias = (ten == 0) ? b0 : (ten == 1) ? b1 : b2;
    OutT* out = (ten == 0) ? o0 : (ten == 1) ? o1 : o2;
    const int nc0 = col0 & (N - 1);

    if constexpr (WITH_FILL) {
        if (ten == 2) {
            // transposed V store: lane holds tokens tok..tok+3 for column colv
            f16* vout = reinterpret_cast<f16*>(o2);
            #pragma unroll
            for (int mi = 0; mi < 4; ++mi)
                #pragma unroll
                for (int ni = 0; ni < 4; ++ni) {
                    const int tok  = row0 + wr * 64 + mi * 16 + quad * 4;
                    const int colv = nc0 + wc * 64 + ni * 16 + l15;
                    const float bvv = bias[colv];
                    f16x4 h4 = {(f16)(acc[mi][ni][0] + bvv), (f16)(acc[mi][ni][1] + bvv),
                                (f16)(acc[mi][ni][2] + bvv), (f16)(acc[mi][ni][3] + bvv)};
                    const int bb = tok >> 11;
                    *(f16x4*)&vout[((size_t)(bb * 1024 + colv)) * 2048 + (tok & 2047)] = h4;
                }
            return;
        }
    }

    #pragma unroll
    for (int mi = 0; mi < 4; ++mi)
        #pragma unroll
        for (int ni = 0; ni < 4; ++ni) {
            const int rbase = row0 + wr * 64 + mi * 16 + quad * 4;
            const int col = nc0 + wc * 64 + ni * 16 + l15;
            const float bv = bias[col];
            #pragma unroll
            for (int r = 0; r < 4; ++r)
                out[(size_t)(rbase + r) * N + col] = (OutT)(acc[mi][ni][r] + bv);
        }
}

// ---------------------------------------------------------------------------
// O-projection GEMM + fill: grid 768 = EXACTLY 3 blocks/CU in uniform
// (G,G,F) triplets -> 512 GEMM + 256 fill (rows [57344,65536)). Previously
// 512 blocks left ~85 CUs idle and the write pipe dark during O-proj.
// 2-phase double-buffered K-loop.
// ---------------------------------------------------------------------------
__global__ __launch_bounds__(256, 3)
void gemm_o64(const f16* __restrict__ A, const f16* __restrict__ W,
              const float* __restrict__ bias, float* __restrict__ out,
              float* __restrict__ fill) {
    constexpr int K = 1024, N = 1024;
    const int t = threadIdx.x;
    const int bid = blockIdx.x;

    const int g3 = bid / 3, l3 = bid - g3 * 3;
    if (l3 == 2) {
        fill_rows32(fill, 57344 + g3 * 32, t);      // fid [0,256) -> rows [57344,65536)
        return;
    }
    const int gid = g3 * 2 + l3;                    // [0,512)

    __shared__ f16 sA[2][64 * 32];
    __shared__ f16 sB[2][128 * 32];

    const int w = t >> 6, l = t & 63, l15 = l & 15, quad = l >> 4;
    const int col_t = gid & 7, row_t = gid >> 3;
    const int row0 = row_t * 64, col0 = col_t * 128;

    f32x4 acc[4][2];
    #pragma unroll
    for (int i = 0; i < 4; ++i)
        #pragma unroll
        for (int j = 0; j < 2; ++j) acc[i][j] = (f32x4){0.f, 0.f, 0.f, 0.f};

    const int arow = t >> 2;          // 0..63
    const int koff = (t & 3) * 8;
    const f16* ga = A + (size_t)(row0 + arow) * K + koff;
    const f16* gb = W + (size_t)(col0 + arow) * K + koff;

    auto STAGE = [&](int buf, int k0) {
        gload_lds16(ga + k0,                  &sA[buf][w * 512]);
        gload_lds16(gb + k0,                  &sB[buf][w * 512]);
        gload_lds16(gb + (size_t)64 * K + k0, &sB[buf][2048 + w * 512]);
    };

    STAGE(0, 0);
    int cur = 0;
    for (int k0 = 0; k0 < K; k0 += 32) {
        if (k0 + 32 < K) {
            STAGE(cur ^ 1, k0 + 32);
            asm volatile("s_waitcnt vmcnt(3)" ::: "memory");
        } else {
            asm volatile("s_waitcnt vmcnt(0)" ::: "memory");
        }
        __builtin_amdgcn_s_barrier();

        f16x8 af[4], bf[2];
        #pragma unroll
        for (int mi = 0; mi < 4; ++mi)
            af[mi] = *(const f16x8*)&sA[cur][(mi * 16 + l15) * 32 + quad * 8];
        #pragma unroll
        for (int ni = 0; ni < 2; ++ni)
            bf[ni] = *(const f16x8*)&sB[cur][(w * 32 + ni * 16 + l15) * 32 + quad * 8];
        #pragma unroll
        for (int mi = 0; mi < 4; ++mi)
            #pragma unroll
            for (int ni = 0; ni < 2; ++ni)
                acc[mi][ni] = __builtin_amdgcn_mfma_f32_16x16x32_f16(af[mi], bf[ni], acc[mi][ni], 0, 0, 0);

        asm volatile("s_waitcnt lgkmcnt(0)" ::: "memory");
        __builtin_amdgcn_s_barrier();
        cur ^= 1;
    }

    #pragma unroll
    for (int mi = 0; mi < 4; ++mi)
        #pragma unroll
        for (int ni = 0; ni < 2; ++ni) {
            const int rbase = row0 + mi * 16 + quad * 4;
            const int col = col0 + w * 32 + ni * 16 + l15;
            const float bv = bias[col];
            #pragma unroll
            for (int r = 0; r < 4; ++r)
                out[(size_t)(rbase + r) * N + col] = acc[mi][ni][r] + bv;
        }
}

// ---------------------------------------------------------------------------
// Fused band attention + fill, STAGGERED: first 768 IDs = (A,A,F) triplets;
// remaining 1024 IDs alternate (A,F). Fill covers rows [32768,57344).
// Q in registers; K/vT staged in LDS; NT band/fill stores.
// ---------------------------------------------------------------------------
__global__ __launch_bounds__(256, 3)
void attn_fused(const f16* __restrict__ qb, const f16* __restrict__ kb,
                const f16* __restrict__ vT, float* __restrict__ attn,
                f16* __restrict__ ctx) {
    const int bid = blockIdx.x;
    const int t = threadIdx.x;

    int aid, fid = -1;
    if (bid < 768) {
        const int g3 = bid / 3, l3 = bid - g3 * 3;
        if (l3 < 2) aid = g3 * 2 + l3;              // [0,512)
        else        fid = g3;                        // [0,256)
    } else {
        const int idx = bid - 768;
        if ((idx & 1) == 0) aid = 512 + (idx >> 1);  // [512,1024)
        else                fid = 256 + (idx >> 1);  // [256,768)
    }
    if (fid >= 0) {
        fill_rows32(attn, 32768 + fid * 32, t);      // rows [32768,57344)
        return;
    }

    __shared__ f16 sK[192 * 72];     // overlaid by sP (64*200 <= 192*72) after QK
    __shared__ f16 sVT[64 * 200];    // vT rows: [d][k window], stride 200 (400 B)
    f16* sP = sK;

    const int w = t >> 6, l = t & 63, l15 = l & 15, quad = l >> 4;
    const int tile = aid & 31, h = (aid >> 5) & 15, b = aid >> 9;
    const int q0 = tile * 64;
    const int jbase = q0 - 64;

    // ---- P0a: Q A-fragments straight to registers (rows w*16+l15) ----
    const f16* qg2 = qb + ((size_t)(b * Sc + q0 + w * 16 + l15)) * Dc + h * HDc;
    const f16x8 aq0 = *(const f16x8*)&qg2[quad * 8];
    const f16x8 aq1 = *(const f16x8*)&qg2[32 + quad * 8];

    // ---- P0b: stage K window (192x64), vT window (64x192) ----
    #pragma unroll
    for (int it = 0; it < 6; ++it) {
        const int idx = it * 256 + t;          // 0..1535
        const int r = idx >> 3, c = (idx & 7) * 8;
        int j = jbase + r;
        j = (j < 0) ? 0 : (j > Sc - 1 ? Sc - 1 : j);
        const size_t goff = ((size_t)(b * Sc + j)) * Dc + h * HDc + c;
        *(uint4*)&sK[r * 72 + c] = *(const uint4*)&kb[goff];
    }
    // vT rows: dd = t>>2 (0..63), chunks of 8 f16 along the token window.
    {
        const f16* vrow = vT + ((size_t)((b * Hc + h) * HDc)) * Sc + jbase;
        const int dd = t >> 2;
        #pragma unroll
        for (int it = 0; it < 6; ++it) {
            const int ch = it * 4 + (t & 3);   // 0..23
            *(uint4*)&sVT[dd * 200 + ch * 8] = *(const uint4*)&vrow[(size_t)dd * Sc + ch * 8];
        }
    }
    __syncthreads();

    // ---- QK^T: S[64x192]; wave w owns rows [16w,16w+16) ----
    f32x4 s[12];
    #pragma unroll
    for (int nt = 0; nt < 12; ++nt) s[nt] = (f32x4){0.f, 0.f, 0.f, 0.f};
    #pragma unroll
    for (int nt = 0; nt < 12; ++nt) {
        const f16x8 bk0 = *(const f16x8*)&sK[(nt * 16 + l15) * 72 + quad * 8];
        s[nt] = __builtin_amdgcn_mfma_f32_16x16x32_f16(aq0, bk0, s[nt], 0, 0, 0);
    }
    #pragma unroll
    for (int nt = 0; nt < 12; ++nt) {
        const f16x8 bk1 = *(const f16x8*)&sK[(nt * 16 + l15) * 72 + 32 + quad * 8];
        s[nt] = __builtin_amdgcn_mfma_f32_16x16x32_f16(aq1, bk1, s[nt], 0, 0, 0);
    }

    // ---- in-register softmax; lane holds rows w*16+quad*4+r, cols nt*16+l15
    float invr[4];
    #pragma unroll
    for (int r = 0; r < 4; ++r) {
        const int row = w * 16 + quad * 4 + r;
        const int lo = (row > 64 - q0) ? row : (64 - q0);
        const int hi2 = (row + 128 < 2111 - q0) ? (row + 128) : (2111 - q0);
        float m = -1e30f;
        #pragma unroll
        for (int nt = 0; nt < 12; ++nt) {
            const int jrel = nt * 16 + l15;
            const float v = s[nt][r] * 0.125f;
            if (jrel >= lo && jrel <= hi2) m = fmaxf(m, v);
        }
        #pragma unroll
        for (int k = 1; k < 16; k <<= 1) m = fmaxf(m, __shfl_xor(m, k, 64));
        float sum = 0.f;
        #pragma unroll
        for (int nt = 0; nt < 12; ++nt) {
            const int jrel = nt * 16 + l15;
            const float v = s[nt][r] * 0.125f;
            const float e = (jrel >= lo && jrel <= hi2) ? __expf(v - m) : 0.f;
            s[nt][r] = e;
            sum += e;
        }
        #pragma unroll
        for (int k = 1; k < 16; k <<= 1) sum += __shfl_xor(sum, k, 64);
        invr[r] = 1.f / sum;
    }
    __syncthreads();   // sK reads done -> safe to overlay sP

    // ---- P2: write P to LDS + aligned global window [a0,a1), NT stores ----
    float* abase = attn + ((size_t)(b * Hc + h) * Sc) * Sc;
    #pragma unroll
    for (int r = 0; r < 4; ++r) {
        const int row = w * 16 + quad * 4 + r;
        const int i = q0 + row;
        const int lo0 = (i > 64) ? (i - 64) : 0;
        const int a0 = lo0 & ~31;
        const int hi0 = (i < Sc - 65) ? (i + 64) : (Sc - 1);
        int a1 = (hi0 + 32) & ~31; if (a1 > Sc) a1 = Sc;
        const int alo = a0 - jbase, ahi = a1 - jbase;
        #pragma unroll
        for (int nt = 0; nt < 12; ++nt) {
            const int jrel = nt * 16 + l15;
            const float p = s[nt][r] * invr[r];
            sP[row * 200 + jrel] = (f16)p;
            if (jrel >= alo && jrel < ahi)
                __builtin_nontemporal_store(p, &abase[(size_t)i * Sc + (jbase + jrel)]);
        }
    }
    __syncthreads();

    // ---- P3: ctx[64x64] = P[64x192] @ V[192x64], V from sVT via b128 ----
    f32x4 o[4];
    #pragma unroll
    for (int dt = 0; dt < 4; ++dt) o[dt] = (f32x4){0.f, 0.f, 0.f, 0.f};
    #pragma unroll
    for (int ks = 0; ks < 6; ++ks) {
        const f16x8 ap = *(const f16x8*)&sP[(w * 16 + l15) * 200 + ks * 32 + quad * 8];
        #pragma unroll
        for (int dt = 0; dt < 4; ++dt) {
            const f16x8 bv = *(const f16x8*)&sVT[(dt * 16 + l15) * 200 + ks * 32 + quad * 8];
            o[dt] = __builtin_amdgcn_mfma_f32_16x16x32_f16(ap, bv, o[dt], 0, 0, 0);
        }
    }
    f16* cg = ctx + ((size_t)(b * Sc + q0)) * Dc + h * HDc;
    #pragma unroll
    for (int dt = 0; dt < 4; ++dt)
        #pragma unroll
        for (int r = 0; r < 4; ++r) {
            const int row = w * 16 + quad * 4 + r;
            cg[(size_t)row * Dc + dt * 16 + l15] = (f16)o[dt][r];
        }
}

// ---------------------------------------------------------------------------
extern "C" void kernel_launch(void* const* d_in, const int* in_sizes, int n_in,
                              void* d_out, int out_size, void* d_ws, size_t ws_size,
                              hipStream_t stream) {
    const float* x  = (const float*)d_in[0];
    const float* Wq = (const float*)d_in[1];
    const float* bq = (const float*)d_in[2];
    const float* Wk = (const float*)d_in[3];
    const float* bk = (const float*)d_in[4];
    const float* Wv = (const float*)d_in[5];
    const float* bv = (const float*)d_in[6];
    const float* Wo = (const float*)d_in[7];
    const float* bo = (const float*)d_in[8];

    float* out  = (float*)d_out;
    float* attn = out + PROJ;

    char* ws = (char*)d_ws;
    f16* Wcat  = (f16*)ws;                 // [4][1024][1024] fp16 = 8 MB
    f16* x_f16 = (f16*)(ws + (size_t)8  * 1024 * 1024);
    f16* q_f16 = (f16*)(ws + (size_t)16 * 1024 * 1024);
    f16* k_f16 = (f16*)(ws + (size_t)24 * 1024 * 1024);
    f16* c_f16 = (f16*)(ws + (size_t)40 * 1024 * 1024);
    // transposed V [2048 d-rows][2048 tokens] fp16 with 512 B guards each side
    f16* vT    = (f16*)(ws + (size_t)48 * 1024 * 1024 + 512);

    pack_all<<<dim3(8193), dim3(256), 0, stream>>>(x, Wq, Wk, Wv, Wo, x_f16, Wcat, vT);

    // QKV GEMM (768) + fill rows [0,32768) (1024), staggered 2:1 head / 1:3 tail
    gemm_mega<f16, true><<<dim3(1792), dim3(256), 0, stream>>>(
        x_f16, Wcat, bq, bk, bv, q_f16, k_f16, vT, attn, 24);

    // attention (1024) + fill rows [32768,57344) (768), staggered
    attn_fused<<<dim3(1792), dim3(256), 0, stream>>>(
        q_f16, k_f16, vT, attn, c_f16);

    // O projection (512) + fill rows [57344,65536) (256), uniform (G,G,F)
    gemm_o64<<<dim3(768), dim3(256), 0, stream>>>(
        c_f16, Wcat + 3 * WN, bo, out, attn);
}